// Round 10
// baseline (1190.244 us; speedup 1.0000x reference)
//
#include <hip/hip_runtime.h>

#define NN 100000
#define NE 3200000
#define HD 64

// two-phase CSR build
#define NBUCK 256
#define BWID 392                                    // 256*392 = 100352 >= NN
#define SLACK 20480                                 // slots/bucket: 12544 real + ~5500 pad + margin
#define COLCAP 13568                                // real cols/bucket cap (12544 + ~9 sigma)
#define OVFCAP 512                                  // overflow pairs/bucket
#define CAP 16                                      // staged pairs per bucket per block
#define P1_EPB 2048                                 // edges per partition block
#define P1_GRID ((NE + P1_EPB - 1) / P1_EPB)        // 1563

#define GB 2048                                     // gather grid (8 blocks/CU, enforced resident)

typedef int   v4i __attribute__((ext_vector_type(4)));
typedef int   v2i __attribute__((ext_vector_type(2)));

__device__ __forceinline__ void fma4(float4& a, float s, const float4& b) {
    a.x = fmaf(s, b.x, a.x); a.y = fmaf(s, b.y, a.y);
    a.z = fmaf(s, b.z, a.z); a.w = fmaf(s, b.w, a.w);
}
__device__ __forceinline__ void add4(float4& a, const float4& b) {
    a.x += b.x; a.y += b.y; a.z += b.z; a.w += b.w;
}

// ---------------- phase 1: bucket partition, LDS-staged, 1 drain/block ----------------
__global__ void __launch_bounds__(256) partition_kernel(
    const int* __restrict__ src, const int* __restrict__ dst,
    int* __restrict__ bctl, v2i* __restrict__ pairs, v2i* __restrict__ povf) {
    __shared__ v2i stage[NBUCK][CAP];
    __shared__ int cnt[NBUCK];
    int t = threadIdx.x;
    cnt[t] = 0;                         // NBUCK == blockDim == 256
    __syncthreads();
    const v4i* d4p = (const v4i*)dst;
    const v4i* s4p = (const v4i*)src;
    const int NE4 = NE / 4;
    int base4 = blockIdx.x * (P1_EPB / 4);
    #pragma unroll
    for (int it = 0; it < P1_EPB / 1024; it++) {
        int i = base4 + it * 256 + t;
        v4i d4 = (v4i){-1, -1, -1, -1};
        v4i s4 = (v4i){0, 0, 0, 0};
        if (i < NE4) {
            d4 = __builtin_nontemporal_load(d4p + i);
            s4 = __builtin_nontemporal_load(s4p + i);
        }
        #pragma unroll
        for (int k = 0; k < 4; k++) {
            int d = d4[k];
            if (d >= 0) {
                int b = (unsigned)d / BWID;
                int slot = atomicAdd(&cnt[b], 1);
                v2i p; p[0] = s4[k]; p[1] = d;
                if (slot < CAP) {
                    stage[b][slot] = p;
                } else {                 // rare overflow -> separate region
                    int o = atomicAdd(&bctl[b * 16 + 2], 1);
                    if (o < OVFCAP) povf[(size_t)b * OVFCAP + o] = p;
                }
            }
        }
    }
    __syncthreads();
    // drain bucket t (single drain per block)
    int c_tot = cnt[t];
    int c = (c_tot > CAP) ? CAP : c_tot;
    int runs = (c + 7) >> 3;             // 0..2
    if (runs) {
        int slots = runs * 8;            // 8 or 16, <= CAP
        for (int m = c; m < slots; m++) { v2i p; p[0] = 0; p[1] = -1; stage[t][m] = p; }
        int gb = atomicAdd(&bctl[t * 16], slots);   // stays multiple of 8
        if (gb + slots <= SLACK) {
            v4i* gp = (v4i*)(pairs + (size_t)t * SLACK + gb);
            const v4i* sp = (const v4i*)&stage[t][0];
            #pragma unroll
            for (int m = 0; m < 8; m++) { if (m < runs * 4) gp[m] = sp[m]; }
        } else {
            for (int m = 0; m < slots && gb + m < SLACK; m++)
                pairs[(size_t)t * SLACK + gb + m] = stage[t][m];
        }
    }
    if (c_tot > 0) atomicAdd(&bctl[t * 16 + 1], c_tot);   // real contribution
}

// ---------------- tiny scan over real bucket counts ----------------
__global__ void bucket_scan_kernel(const int* __restrict__ bctl,
                                   int* __restrict__ bbase, int* __restrict__ rowptr) {
    __shared__ int s[NBUCK];
    int t = threadIdx.x;
    int v = bctl[t * 16 + 1];
    s[t] = v; __syncthreads();
    for (int off = 1; off < NBUCK; off <<= 1) {
        int x = (t >= off) ? s[t - off] : 0;
        __syncthreads();
        s[t] += x;
        __syncthreads();
    }
    bbase[t] = s[t] - v;                 // exclusive prefix of real counts
    if (t == NBUCK - 1) rowptr[NN] = s[t];   // == NE
}

// ---------------- phase 2: per-bucket hist + scan + LDS scatter ----------------
__global__ void __launch_bounds__(256) csr_fill_kernel(
    const v2i* __restrict__ pairs, const v2i* __restrict__ povf,
    const int* __restrict__ bctl, const int* __restrict__ bbase,
    int* __restrict__ rowptr, float* __restrict__ dinv, int* __restrict__ col) {
    __shared__ int hist[BWID];
    __shared__ int rp[BWID];
    __shared__ int cur[BWID];
    __shared__ int sc[256];
    __shared__ int cols[COLCAP];
    int b = blockIdx.x, t = threadIdx.x;
    int lo = b * BWID;
    int hi = min(lo + BWID, NN);
    int nw = hi - lo;
    for (int i = t; i < BWID; i += 256) { hist[i] = 0; cur[i] = 0; }
    __syncthreads();
    int np = bctl[b * 16];     if (np > SLACK) np = SLACK;
    int nov = bctl[b * 16 + 2]; if (nov > OVFCAP) nov = OVFCAP;
    int base = bbase[b];
    const v2i* pb = pairs + (size_t)b * SLACK;
    const v2i* ob = povf + (size_t)b * OVFCAP;
    // pass 1: histogram (skip sentinels)
    for (int i = t; i < np; i += 256) {
        v2i p = pb[i];
        if (p[1] >= 0) atomicAdd(&hist[p[1] - lo], 1);
    }
    for (int i = t; i < nov; i += 256) {
        v2i p = ob[i];
        atomicAdd(&hist[p[1] - lo], 1);
    }
    __syncthreads();
    // exclusive scan of hist -> rp (2 elements per thread)
    int h0 = 0, s2 = 0;
    if (2 * t < BWID) {
        h0 = hist[2 * t];
        int h1 = (2 * t + 1 < BWID) ? hist[2 * t + 1] : 0;
        s2 = h0 + h1;
    }
    sc[t] = s2; __syncthreads();
    for (int off = 1; off < 256; off <<= 1) {
        int x = (t >= off) ? sc[t - off] : 0;
        __syncthreads();
        sc[t] += x;
        __syncthreads();
    }
    if (2 * t < BWID) {
        int ex = sc[t] - s2;
        rp[2 * t] = ex;
        if (2 * t + 1 < BWID) rp[2 * t + 1] = ex + h0;
    }
    __syncthreads();
    // rowptr + dinv slices (coalesced)
    for (int i = t; i < nw; i += 256) {
        rowptr[lo + i] = base + rp[i];
        dinv[lo + i] = 1.0f / sqrtf((float)(hist[i] + 1));  // +1 self-loop
    }
    // pass 2: scatter into LDS
    for (int i = t; i < np; i += 256) {
        v2i p = pb[i];
        if (p[1] >= 0) {
            int li = p[1] - lo;
            int slot = atomicAdd(&cur[li], 1);
            int o = rp[li] + slot;
            if (o < COLCAP) cols[o] = p[0];
        }
    }
    for (int i = t; i < nov; i += 256) {
        v2i p = ob[i];
        int li = p[1] - lo;
        int slot = atomicAdd(&cur[li], 1);
        int o = rp[li] + slot;
        if (o < COLCAP) cols[o] = p[0];
    }
    __syncthreads();
    // contiguous col write (real count only)
    int nreal = bctl[b * 16 + 1]; if (nreal > COLCAP) nreal = COLCAP;
    for (int i = t; i < nreal; i += 256)
        col[base + i] = cols[i];
}

// ---------------- fused modality encoders + GCN layer-0 matmul ----------------
__global__ void __launch_bounds__(256) encmm0_kernel(
    const float* __restrict__ xf, const float* __restrict__ xw, const float* __restrict__ xt,
    const float* __restrict__ Wf, const float* __restrict__ bf,
    const float* __restrict__ Ww, const float* __restrict__ bw,
    const float* __restrict__ Wt, const float* __restrict__ bt,
    const float* __restrict__ W0, const float* __restrict__ dinv,
    float* __restrict__ h) {
    __shared__ float xin[64][32];    // fire[0..7], wea[8..19], ter[20..29]
    __shared__ float wenc[30][64];   // encoder weights (rows match xin cols)
    __shared__ float bs[192];        // encoder biases
    __shared__ float xs[64][36];     // encoder outputs for current 32-slice (+4 pad)
    __shared__ float ws[32][64];     // W0 rows for current slice
    int t = threadIdx.x;
    int n0 = blockIdx.x * 64;

    {   // stage raw inputs
        const float4* xf4 = (const float4*)xf;
        for (int i = t; i < 128; i += 256) {
            int n = i >> 1, q = i & 1;
            int gn = n0 + n;
            float4 v = make_float4(0, 0, 0, 0);
            if (gn < NN) v = xf4[(size_t)gn * 2 + q];
            *(float4*)&xin[n][q * 4] = v;
        }
        const float4* xw4 = (const float4*)xw;
        for (int i = t; i < 192; i += 256) {
            int n = i / 3, q = i - n * 3;
            int gn = n0 + n;
            float4 v = make_float4(0, 0, 0, 0);
            if (gn < NN) v = xw4[(size_t)gn * 3 + q];
            *(float4*)&xin[n][8 + q * 4] = v;
        }
        const float2* xt2 = (const float2*)xt;
        for (int i = t; i < 320; i += 256) {
            int n = i / 5, q = i - n * 5;
            int gn = n0 + n;
            float2 v = make_float2(0, 0);
            if (gn < NN) v = xt2[(size_t)gn * 5 + q];
            *(float2*)&xin[n][20 + q * 2] = v;
        }
        // stage encoder weights: rows 0-7 Wf, 8-19 Ww, 20-29 Wt
        for (int i = t; i < 480; i += 256) {
            int r = i >> 4, q = i & 15;
            float4 v;
            if (r < 8)       v = ((const float4*)Wf)[r * 16 + q];
            else if (r < 20) v = ((const float4*)Ww)[(r - 8) * 16 + q];
            else             v = ((const float4*)Wt)[(r - 20) * 16 + q];
            *(float4*)&wenc[r][q * 4] = v;
        }
        // stage encoder biases
        if (t < 192) bs[t] = (t < 64) ? bf[t] : (t < 128) ? bw[t - 64] : bt[t - 128];
    }

    int cg = t & 15, ng = t >> 4;
    int c0 = cg * 4;
    float4 acc[4];
    #pragma unroll
    for (int i = 0; i < 4; i++) acc[i] = make_float4(0, 0, 0, 0);

    for (int kq = 0; kq < 6; kq++) {
        __syncthreads();
        {   // stage W0 slice rows [kq*32, kq*32+32)
            const float4* W04 = (const float4*)W0;
            float4* ws4 = (float4*)&ws[0][0];
            for (int i = t; i < 512; i += 256)
                ws4[i] = W04[(size_t)kq * 512 + i];
        }
        // compute encoder outputs for this slice (uniform modality per kq)
        int coff = (kq < 2) ? kq * 32 : (kq < 4) ? (kq - 2) * 32 : (kq - 4) * 32;
        if (kq < 2) {
            for (int i = t; i < 2048; i += 256) {
                int n = i >> 5, kk = i & 31;
                float a = bs[kq * 32 + kk];
                #pragma unroll
                for (int k = 0; k < 8; k++) a = fmaf(xin[n][k], wenc[k][coff + kk], a);
                xs[n][kk] = fmaxf(a, 0.f);
            }
        } else if (kq < 4) {
            for (int i = t; i < 2048; i += 256) {
                int n = i >> 5, kk = i & 31;
                float a = bs[kq * 32 + kk];
                #pragma unroll
                for (int k = 0; k < 12; k++) a = fmaf(xin[n][8 + k], wenc[8 + k][coff + kk], a);
                xs[n][kk] = fmaxf(a, 0.f);
            }
        } else {
            for (int i = t; i < 2048; i += 256) {
                int n = i >> 5, kk = i & 31;
                float a = bs[kq * 32 + kk];
                #pragma unroll
                for (int k = 0; k < 10; k++) a = fmaf(xin[n][20 + k], wenc[20 + k][coff + kk], a);
                xs[n][kk] = fmaxf(a, 0.f);
            }
        }
        __syncthreads();
        // register-blocked fma over this 32-slice
        for (int k = 0; k < 32; k += 4) {
            float4 b0 = *(const float4*)&ws[k + 0][c0];
            float4 b1 = *(const float4*)&ws[k + 1][c0];
            float4 b2 = *(const float4*)&ws[k + 2][c0];
            float4 b3 = *(const float4*)&ws[k + 3][c0];
            #pragma unroll
            for (int i = 0; i < 4; i++) {
                float4 a = *(const float4*)&xs[ng * 4 + i][k];
                fma4(acc[i], a.x, b0); fma4(acc[i], a.y, b1);
                fma4(acc[i], a.z, b2); fma4(acc[i], a.w, b3);
            }
        }
    }
    float4* h4 = (float4*)h;
    #pragma unroll
    for (int i = 0; i < 4; i++) {
        int gn = n0 + ng * 4 + i;
        if (gn < NN) {
            float dn = dinv[gn];
            float4 v = acc[i];
            v.x *= dn; v.y *= dn; v.z *= dn; v.w *= dn;
            h4[(size_t)gn * 16 + cg] = v;
        }
    }
}

// ---------------- fused CSR gather + finalize + next-layer 64x64 matmul ----------------
// Grid-stride persistent waves; W staged once per block. __launch_bounds__(256,8)
// caps VGPR at 64 so all 8 blocks/CU (GB=2048) are RESIDENT SIMULTANEOUSLY --
// round 9's 84-VGPR build fit only 6/CU, leaving 512 blocks to run in a nearly
// idle second shift (occupancy 28%, 1.5x dur). hout stored non-temporally.
__global__ void __launch_bounds__(256, 8) gather_mm_kernel(
    const int* __restrict__ col, const int* __restrict__ rowptr,
    const float* __restrict__ dinv, const float* __restrict__ h,
    const float* __restrict__ bias, const float* __restrict__ W,
    float* __restrict__ hout) {
    __shared__ float Wl[64][64];
    int t = threadIdx.x;
    {
        const float4* W4 = (const float4*)W;
        float4* wl4 = (float4*)&Wl[0][0];
        for (int i = t; i < 1024; i += 256) wl4[i] = W4[i];
    }
    __syncthreads();
    int l = t & 63;
    int g = l >> 4;      // edge sub-slot 0..3
    int q = l & 15;      // float4 slot 0..15
    const float4* h4 = (const float4*)h;
    int wid = (blockIdx.x * 256 + t) >> 6;      // global wave id
    const int nwave = (GB * 256) >> 6;          // 8192 waves
    for (int n = wid; n < NN; n += nwave) {
        float4 acc = make_float4(0, 0, 0, 0);
        int r0 = rowptr[n], r1 = rowptr[n + 1];
        for (int base = r0; base < r1; base += 64) {
            int cnt = min(64, r1 - base);
            int pv = NN;                          // sentinel: zero row
            if (l < cnt) pv = __builtin_nontemporal_load(col + base + l);
            int steps = (cnt + 3) >> 2;
            int j = 0;
            for (; j + 4 <= steps; j += 4) {
                int e0 = (j + 0) * 4 + g, e1 = (j + 1) * 4 + g;
                int e2 = (j + 2) * 4 + g, e3 = (j + 3) * 4 + g;
                int s0 = __shfl(pv, e0);
                int s1 = __shfl(pv, e1);
                int s2 = __shfl(pv, e2);
                int s3 = __shfl(pv, e3);
                float4 v0 = h4[(size_t)s0 * 16 + q];
                float4 v1 = h4[(size_t)s1 * 16 + q];
                float4 v2 = h4[(size_t)s2 * 16 + q];
                float4 v3 = h4[(size_t)s3 * 16 + q];
                add4(acc, v0); add4(acc, v1);
                add4(acc, v2); add4(acc, v3);
            }
            for (; j < steps; j++) {
                int e = j * 4 + g;
                int s = __shfl(pv, e);
                float4 v = h4[(size_t)s * 16 + q];
                add4(acc, v);
            }
        }
        acc.x += __shfl_xor(acc.x, 16); acc.y += __shfl_xor(acc.y, 16);
        acc.z += __shfl_xor(acc.z, 16); acc.w += __shfl_xor(acc.w, 16);
        acc.x += __shfl_xor(acc.x, 32); acc.y += __shfl_xor(acc.y, 32);
        acc.z += __shfl_xor(acc.z, 32); acc.w += __shfl_xor(acc.w, 32);
        // layer output r (all lanes; q-slot replicated)
        float dn = dinv[n];
        float4 hn = h4[(size_t)n * 16 + q];   // hs[n] = h[n]*dinv[n]
        float4 b4 = ((const float4*)bias)[q];
        float4 r;
        r.x = fmaxf(fmaf(dn, acc.x + hn.x, b4.x), 0.f);
        r.y = fmaxf(fmaf(dn, acc.y + hn.y, b4.y), 0.f);
        r.z = fmaxf(fmaf(dn, acc.z + hn.z, b4.z), 0.f);
        r.w = fmaxf(fmaf(dn, acc.w + hn.w, b4.w), 0.f);
        // next-layer matmul: lane l computes output column l
        float oc = 0.f;
        #pragma unroll
        for (int qq = 0; qq < 16; qq++) {
            float rx = __shfl(r.x, qq);
            float ry = __shfl(r.y, qq);
            float rz = __shfl(r.z, qq);
            float rw = __shfl(r.w, qq);
            oc = fmaf(rx, Wl[qq * 4 + 0][l], oc);
            oc = fmaf(ry, Wl[qq * 4 + 1][l], oc);
            oc = fmaf(rz, Wl[qq * 4 + 2][l], oc);
            oc = fmaf(rw, Wl[qq * 4 + 3][l], oc);
        }
        __builtin_nontemporal_store(oc * dn, &hout[(size_t)n * 64 + l]);
    }
}

// ---------------- fused CSR gather + finalize + output MLP ----------------
__global__ void __launch_bounds__(256, 8) gather_mlp_kernel(
    const int* __restrict__ col, const int* __restrict__ rowptr,
    const float* __restrict__ dinv, const float* __restrict__ h,
    const float* __restrict__ bias, const float* __restrict__ w1,
    const float* __restrict__ b1, const float* __restrict__ w2,
    const float* __restrict__ b2, float* __restrict__ out) {
    __shared__ float W1l[64][32];   // lane c reads W1l[k][c]: distinct banks
    __shared__ float w2l[32];
    __shared__ float b1l[32];
    int t = threadIdx.x;
    {
        const float4* w14 = (const float4*)w1;
        float4* wl4 = (float4*)&W1l[0][0];
        for (int i = t; i < 512; i += 256) wl4[i] = w14[i];
        if (t < 32) { w2l[t] = w2[t]; b1l[t] = b1[t]; }
    }
    __syncthreads();
    int l = t & 63;
    int g = l >> 4;
    int q = l & 15;
    const float4* h4 = (const float4*)h;
    int wid = (blockIdx.x * 256 + t) >> 6;
    const int nwave = (GB * 256) >> 6;
    for (int n = wid; n < NN; n += nwave) {
        float4 acc = make_float4(0, 0, 0, 0);
        int r0 = rowptr[n], r1 = rowptr[n + 1];
        for (int base = r0; base < r1; base += 64) {
            int cnt = min(64, r1 - base);
            int pv = NN;
            if (l < cnt) pv = __builtin_nontemporal_load(col + base + l);
            int steps = (cnt + 3) >> 2;
            int j = 0;
            for (; j + 4 <= steps; j += 4) {
                int e0 = (j + 0) * 4 + g, e1 = (j + 1) * 4 + g;
                int e2 = (j + 2) * 4 + g, e3 = (j + 3) * 4 + g;
                int s0 = __shfl(pv, e0);
                int s1 = __shfl(pv, e1);
                int s2 = __shfl(pv, e2);
                int s3 = __shfl(pv, e3);
                float4 v0 = h4[(size_t)s0 * 16 + q];
                float4 v1 = h4[(size_t)s1 * 16 + q];
                float4 v2 = h4[(size_t)s2 * 16 + q];
                float4 v3 = h4[(size_t)s3 * 16 + q];
                add4(acc, v0); add4(acc, v1);
                add4(acc, v2); add4(acc, v3);
            }
            for (; j < steps; j++) {
                int e = j * 4 + g;
                int s = __shfl(pv, e);
                float4 v = h4[(size_t)s * 16 + q];
                add4(acc, v);
            }
        }
        acc.x += __shfl_xor(acc.x, 16); acc.y += __shfl_xor(acc.y, 16);
        acc.z += __shfl_xor(acc.z, 16); acc.w += __shfl_xor(acc.w, 16);
        acc.x += __shfl_xor(acc.x, 32); acc.y += __shfl_xor(acc.y, 32);
        acc.z += __shfl_xor(acc.z, 32); acc.w += __shfl_xor(acc.w, 32);
        float dn = dinv[n];
        float4 hn = h4[(size_t)n * 16 + q];
        float4 b4 = ((const float4*)bias)[q];
        float4 r;
        r.x = fmaxf(fmaf(dn, acc.x + hn.x, b4.x), 0.f);
        r.y = fmaxf(fmaf(dn, acc.y + hn.y, b4.y), 0.f);
        r.z = fmaxf(fmaf(dn, acc.z + hn.z, b4.z), 0.f);
        r.w = fmaxf(fmaf(dn, acc.w + hn.w, b4.w), 0.f);
        // output MLP: hidden unit c = l&31
        int c = l & 31;
        float a2 = b1l[c];
        #pragma unroll
        for (int qq = 0; qq < 16; qq++) {
            float rx = __shfl(r.x, qq);
            float ry = __shfl(r.y, qq);
            float rz = __shfl(r.z, qq);
            float rw = __shfl(r.w, qq);
            a2 = fmaf(rx, W1l[qq * 4 + 0][c], a2);
            a2 = fmaf(ry, W1l[qq * 4 + 1][c], a2);
            a2 = fmaf(rz, W1l[qq * 4 + 2][c], a2);
            a2 = fmaf(rw, W1l[qq * 4 + 3][c], a2);
        }
        float v = fmaxf(a2, 0.f) * w2l[c];
        v += __shfl_xor(v, 1); v += __shfl_xor(v, 2);
        v += __shfl_xor(v, 4); v += __shfl_xor(v, 8);
        v += __shfl_xor(v, 16);
        if (l == 0) __builtin_nontemporal_store(v + b2[0], &out[n]);
    }
}

extern "C" void kernel_launch(void* const* d_in, const int* in_sizes, int n_in,
                              void* d_out, int out_size, void* d_ws, size_t ws_size,
                              hipStream_t stream) {
    const float* xf = (const float*)d_in[0];
    const float* xw = (const float*)d_in[1];
    const float* xt = (const float*)d_in[2];
    const int*   ei = (const int*)d_in[3];
    const int*   src = ei;
    const int*   dst = ei + NE;
    const float* Wf = (const float*)d_in[4];
    const float* bf = (const float*)d_in[5];
    const float* Ww = (const float*)d_in[6];
    const float* bw = (const float*)d_in[7];
    const float* Wt = (const float*)d_in[8];
    const float* bt = (const float*)d_in[9];
    const float* W0 = (const float*)d_in[10];
    const float* b0 = (const float*)d_in[11];
    const float* W1 = (const float*)d_in[12];
    const float* b1 = (const float*)d_in[13];
    const float* W2 = (const float*)d_in[14];
    const float* b2 = (const float*)d_in[15];
    const float* ow1 = (const float*)d_in[16];
    const float* ob1 = (const float*)d_in[17];
    const float* ow2 = (const float*)d_in[18];
    const float* ob2 = (const float*)d_in[19];
    float* out = (float*)d_out;

    // workspace layout. pairs (42 MB) ALIASES hA+hB: dead before encmm0 writes hA.
    char* w = (char*)d_ws;
    float* hA     = (float*)w;  w += (size_t)(NN + 1) * 64 * 4;      // 25.6 MB (+zero row)
    float* hB     = (float*)w;  w += (size_t)(NN + 1) * 64 * 4;      // 25.6 MB (+zero row)
    int*   col    = (int*)w;    w += (size_t)NE * 4;                 // 12.8 MB
    v2i*   povf   = (v2i*)w;    w += (size_t)NBUCK * OVFCAP * 8;     // 1 MB
    float* dinv   = (float*)w;  w += (size_t)NN * 4;
    int*   rowptr = (int*)w;    w += (size_t)(NN + 1) * 4;
    int*   bctl   = (int*)w;    w += (size_t)NBUCK * 16 * 4;         // 16 KB (padded lines)
    int*   bbase  = (int*)w;    w += (size_t)NBUCK * 4;
    v2i*   pairs  = (v2i*)hA;                                        // alias (42 MB <= 51.2 MB)

    // ---- CSR build (two-phase, line-staged; reused by all 3 layers) ----
    hipMemsetAsync(bctl, 0, (size_t)NBUCK * 16 * 4, stream);
    partition_kernel<<<P1_GRID, 256, 0, stream>>>(src, dst, bctl, pairs, povf);
    bucket_scan_kernel<<<1, NBUCK, 0, stream>>>(bctl, bbase, rowptr);
    csr_fill_kernel<<<NBUCK, 256, 0, stream>>>(pairs, povf, bctl, bbase, rowptr, dinv, col);
    // sentinel zero rows (after pairs is dead)
    hipMemsetAsync(hA + (size_t)NN * 64, 0, 64 * 4, stream);
    hipMemsetAsync(hB + (size_t)NN * 64, 0, 64 * 4, stream);

    // ---- layer 0: fused encoders + matmul (scaled) -> hA ----
    encmm0_kernel<<<(NN + 63) / 64, 256, 0, stream>>>(xf, xw, xt, Wf, bf, Ww, bw, Wt, bt, W0, dinv, hA);
    // ---- gather(b0) + mm(W1) : hA -> hB ----
    gather_mm_kernel<<<GB, 256, 0, stream>>>(col, rowptr, dinv, hA, b0, W1, hB);
    // ---- gather(b1) + mm(W2) : hB -> hA ----
    gather_mm_kernel<<<GB, 256, 0, stream>>>(col, rowptr, dinv, hB, b1, W2, hA);
    // ---- gather(b2) + output MLP : hA -> out ----
    gather_mlp_kernel<<<GB, 256, 0, stream>>>(col, rowptr, dinv, hA, b2, ow1, ob1, ow2, ob2, out);
}

// Round 11
// 1030.902 us; speedup vs baseline: 1.1546x; 1.1546x over previous
//
#include <hip/hip_runtime.h>

#define NN 100000
#define NE 3200000
#define HD 64

// two-phase CSR build
#define NBUCK 256
#define BWID 392                                    // 256*392 = 100352 >= NN
#define SLACK 20480                                 // slots/bucket: 12544 real + ~5500 pad + margin
#define COLCAP 13568                                // real cols/bucket cap (12544 + ~9 sigma)
#define OVFCAP 512                                  // overflow pairs/bucket
#define CAP 16                                      // staged pairs per bucket per block
#define P1_EPB 2048                                 // edges per partition block
#define P1_GRID ((NE + P1_EPB - 1) / P1_EPB)        // 1563

#define GB 1536                                     // gather grid: 6 blocks/CU -- matches the
                                                    // natural 84-VGPR residency (512/84 = 6
                                                    // waves/SIMD), single shift, NO spills

typedef int   v4i __attribute__((ext_vector_type(4)));
typedef int   v2i __attribute__((ext_vector_type(2)));

__device__ __forceinline__ void fma4(float4& a, float s, const float4& b) {
    a.x = fmaf(s, b.x, a.x); a.y = fmaf(s, b.y, a.y);
    a.z = fmaf(s, b.z, a.z); a.w = fmaf(s, b.w, a.w);
}
__device__ __forceinline__ void add4(float4& a, const float4& b) {
    a.x += b.x; a.y += b.y; a.z += b.z; a.w += b.w;
}

// ---------------- phase 1: bucket partition, LDS-staged, 1 drain/block ----------------
__global__ void __launch_bounds__(256) partition_kernel(
    const int* __restrict__ src, const int* __restrict__ dst,
    int* __restrict__ bctl, v2i* __restrict__ pairs, v2i* __restrict__ povf) {
    __shared__ v2i stage[NBUCK][CAP];
    __shared__ int cnt[NBUCK];
    int t = threadIdx.x;
    cnt[t] = 0;                         // NBUCK == blockDim == 256
    __syncthreads();
    const v4i* d4p = (const v4i*)dst;
    const v4i* s4p = (const v4i*)src;
    const int NE4 = NE / 4;
    int base4 = blockIdx.x * (P1_EPB / 4);
    #pragma unroll
    for (int it = 0; it < P1_EPB / 1024; it++) {
        int i = base4 + it * 256 + t;
        v4i d4 = (v4i){-1, -1, -1, -1};
        v4i s4 = (v4i){0, 0, 0, 0};
        if (i < NE4) {
            d4 = __builtin_nontemporal_load(d4p + i);
            s4 = __builtin_nontemporal_load(s4p + i);
        }
        #pragma unroll
        for (int k = 0; k < 4; k++) {
            int d = d4[k];
            if (d >= 0) {
                int b = (unsigned)d / BWID;
                int slot = atomicAdd(&cnt[b], 1);
                v2i p; p[0] = s4[k]; p[1] = d;
                if (slot < CAP) {
                    stage[b][slot] = p;
                } else {                 // rare overflow -> separate region
                    int o = atomicAdd(&bctl[b * 16 + 2], 1);
                    if (o < OVFCAP) povf[(size_t)b * OVFCAP + o] = p;
                }
            }
        }
    }
    __syncthreads();
    // drain bucket t (single drain per block)
    int c_tot = cnt[t];
    int c = (c_tot > CAP) ? CAP : c_tot;
    int runs = (c + 7) >> 3;             // 0..2
    if (runs) {
        int slots = runs * 8;            // 8 or 16, <= CAP
        for (int m = c; m < slots; m++) { v2i p; p[0] = 0; p[1] = -1; stage[t][m] = p; }
        int gb = atomicAdd(&bctl[t * 16], slots);   // stays multiple of 8
        if (gb + slots <= SLACK) {
            v4i* gp = (v4i*)(pairs + (size_t)t * SLACK + gb);
            const v4i* sp = (const v4i*)&stage[t][0];
            #pragma unroll
            for (int m = 0; m < 8; m++) { if (m < runs * 4) gp[m] = sp[m]; }
        } else {
            for (int m = 0; m < slots && gb + m < SLACK; m++)
                pairs[(size_t)t * SLACK + gb + m] = stage[t][m];
        }
    }
    if (c_tot > 0) atomicAdd(&bctl[t * 16 + 1], c_tot);   // real contribution
}

// ---------------- tiny scan over real bucket counts ----------------
__global__ void bucket_scan_kernel(const int* __restrict__ bctl,
                                   int* __restrict__ bbase, int* __restrict__ rowptr) {
    __shared__ int s[NBUCK];
    int t = threadIdx.x;
    int v = bctl[t * 16 + 1];
    s[t] = v; __syncthreads();
    for (int off = 1; off < NBUCK; off <<= 1) {
        int x = (t >= off) ? s[t - off] : 0;
        __syncthreads();
        s[t] += x;
        __syncthreads();
    }
    bbase[t] = s[t] - v;                 // exclusive prefix of real counts
    if (t == NBUCK - 1) rowptr[NN] = s[t];   // == NE
}

// ---------------- phase 2: per-bucket hist + scan + LDS scatter ----------------
__global__ void __launch_bounds__(256) csr_fill_kernel(
    const v2i* __restrict__ pairs, const v2i* __restrict__ povf,
    const int* __restrict__ bctl, const int* __restrict__ bbase,
    int* __restrict__ rowptr, float* __restrict__ dinv, int* __restrict__ col) {
    __shared__ int hist[BWID];
    __shared__ int rp[BWID];
    __shared__ int cur[BWID];
    __shared__ int sc[256];
    __shared__ int cols[COLCAP];
    int b = blockIdx.x, t = threadIdx.x;
    int lo = b * BWID;
    int hi = min(lo + BWID, NN);
    int nw = hi - lo;
    for (int i = t; i < BWID; i += 256) { hist[i] = 0; cur[i] = 0; }
    __syncthreads();
    int np = bctl[b * 16];     if (np > SLACK) np = SLACK;
    int nov = bctl[b * 16 + 2]; if (nov > OVFCAP) nov = OVFCAP;
    int base = bbase[b];
    const v2i* pb = pairs + (size_t)b * SLACK;
    const v2i* ob = povf + (size_t)b * OVFCAP;
    // pass 1: histogram (skip sentinels)
    for (int i = t; i < np; i += 256) {
        v2i p = pb[i];
        if (p[1] >= 0) atomicAdd(&hist[p[1] - lo], 1);
    }
    for (int i = t; i < nov; i += 256) {
        v2i p = ob[i];
        atomicAdd(&hist[p[1] - lo], 1);
    }
    __syncthreads();
    // exclusive scan of hist -> rp (2 elements per thread)
    int h0 = 0, s2 = 0;
    if (2 * t < BWID) {
        h0 = hist[2 * t];
        int h1 = (2 * t + 1 < BWID) ? hist[2 * t + 1] : 0;
        s2 = h0 + h1;
    }
    sc[t] = s2; __syncthreads();
    for (int off = 1; off < 256; off <<= 1) {
        int x = (t >= off) ? sc[t - off] : 0;
        __syncthreads();
        sc[t] += x;
        __syncthreads();
    }
    if (2 * t < BWID) {
        int ex = sc[t] - s2;
        rp[2 * t] = ex;
        if (2 * t + 1 < BWID) rp[2 * t + 1] = ex + h0;
    }
    __syncthreads();
    // rowptr + dinv slices (coalesced)
    for (int i = t; i < nw; i += 256) {
        rowptr[lo + i] = base + rp[i];
        dinv[lo + i] = 1.0f / sqrtf((float)(hist[i] + 1));  // +1 self-loop
    }
    // pass 2: scatter into LDS
    for (int i = t; i < np; i += 256) {
        v2i p = pb[i];
        if (p[1] >= 0) {
            int li = p[1] - lo;
            int slot = atomicAdd(&cur[li], 1);
            int o = rp[li] + slot;
            if (o < COLCAP) cols[o] = p[0];
        }
    }
    for (int i = t; i < nov; i += 256) {
        v2i p = ob[i];
        int li = p[1] - lo;
        int slot = atomicAdd(&cur[li], 1);
        int o = rp[li] + slot;
        if (o < COLCAP) cols[o] = p[0];
    }
    __syncthreads();
    // contiguous col write (real count only)
    int nreal = bctl[b * 16 + 1]; if (nreal > COLCAP) nreal = COLCAP;
    for (int i = t; i < nreal; i += 256)
        col[base + i] = cols[i];
}

// ---------------- fused modality encoders + GCN layer-0 matmul ----------------
__global__ void __launch_bounds__(256) encmm0_kernel(
    const float* __restrict__ xf, const float* __restrict__ xw, const float* __restrict__ xt,
    const float* __restrict__ Wf, const float* __restrict__ bf,
    const float* __restrict__ Ww, const float* __restrict__ bw,
    const float* __restrict__ Wt, const float* __restrict__ bt,
    const float* __restrict__ W0, const float* __restrict__ dinv,
    float* __restrict__ h) {
    __shared__ float xin[64][32];    // fire[0..7], wea[8..19], ter[20..29]
    __shared__ float wenc[30][64];   // encoder weights (rows match xin cols)
    __shared__ float bs[192];        // encoder biases
    __shared__ float xs[64][36];     // encoder outputs for current 32-slice (+4 pad)
    __shared__ float ws[32][64];     // W0 rows for current slice
    int t = threadIdx.x;
    int n0 = blockIdx.x * 64;

    {   // stage raw inputs
        const float4* xf4 = (const float4*)xf;
        for (int i = t; i < 128; i += 256) {
            int n = i >> 1, q = i & 1;
            int gn = n0 + n;
            float4 v = make_float4(0, 0, 0, 0);
            if (gn < NN) v = xf4[(size_t)gn * 2 + q];
            *(float4*)&xin[n][q * 4] = v;
        }
        const float4* xw4 = (const float4*)xw;
        for (int i = t; i < 192; i += 256) {
            int n = i / 3, q = i - n * 3;
            int gn = n0 + n;
            float4 v = make_float4(0, 0, 0, 0);
            if (gn < NN) v = xw4[(size_t)gn * 3 + q];
            *(float4*)&xin[n][8 + q * 4] = v;
        }
        const float2* xt2 = (const float2*)xt;
        for (int i = t; i < 320; i += 256) {
            int n = i / 5, q = i - n * 5;
            int gn = n0 + n;
            float2 v = make_float2(0, 0);
            if (gn < NN) v = xt2[(size_t)gn * 5 + q];
            *(float2*)&xin[n][20 + q * 2] = v;
        }
        // stage encoder weights: rows 0-7 Wf, 8-19 Ww, 20-29 Wt
        for (int i = t; i < 480; i += 256) {
            int r = i >> 4, q = i & 15;
            float4 v;
            if (r < 8)       v = ((const float4*)Wf)[r * 16 + q];
            else if (r < 20) v = ((const float4*)Ww)[(r - 8) * 16 + q];
            else             v = ((const float4*)Wt)[(r - 20) * 16 + q];
            *(float4*)&wenc[r][q * 4] = v;
        }
        // stage encoder biases
        if (t < 192) bs[t] = (t < 64) ? bf[t] : (t < 128) ? bw[t - 64] : bt[t - 128];
    }

    int cg = t & 15, ng = t >> 4;
    int c0 = cg * 4;
    float4 acc[4];
    #pragma unroll
    for (int i = 0; i < 4; i++) acc[i] = make_float4(0, 0, 0, 0);

    for (int kq = 0; kq < 6; kq++) {
        __syncthreads();
        {   // stage W0 slice rows [kq*32, kq*32+32)
            const float4* W04 = (const float4*)W0;
            float4* ws4 = (float4*)&ws[0][0];
            for (int i = t; i < 512; i += 256)
                ws4[i] = W04[(size_t)kq * 512 + i];
        }
        // compute encoder outputs for this slice (uniform modality per kq)
        int coff = (kq < 2) ? kq * 32 : (kq < 4) ? (kq - 2) * 32 : (kq - 4) * 32;
        if (kq < 2) {
            for (int i = t; i < 2048; i += 256) {
                int n = i >> 5, kk = i & 31;
                float a = bs[kq * 32 + kk];
                #pragma unroll
                for (int k = 0; k < 8; k++) a = fmaf(xin[n][k], wenc[k][coff + kk], a);
                xs[n][kk] = fmaxf(a, 0.f);
            }
        } else if (kq < 4) {
            for (int i = t; i < 2048; i += 256) {
                int n = i >> 5, kk = i & 31;
                float a = bs[kq * 32 + kk];
                #pragma unroll
                for (int k = 0; k < 12; k++) a = fmaf(xin[n][8 + k], wenc[8 + k][coff + kk], a);
                xs[n][kk] = fmaxf(a, 0.f);
            }
        } else {
            for (int i = t; i < 2048; i += 256) {
                int n = i >> 5, kk = i & 31;
                float a = bs[kq * 32 + kk];
                #pragma unroll
                for (int k = 0; k < 10; k++) a = fmaf(xin[n][20 + k], wenc[20 + k][coff + kk], a);
                xs[n][kk] = fmaxf(a, 0.f);
            }
        }
        __syncthreads();
        // register-blocked fma over this 32-slice
        for (int k = 0; k < 32; k += 4) {
            float4 b0 = *(const float4*)&ws[k + 0][c0];
            float4 b1 = *(const float4*)&ws[k + 1][c0];
            float4 b2 = *(const float4*)&ws[k + 2][c0];
            float4 b3 = *(const float4*)&ws[k + 3][c0];
            #pragma unroll
            for (int i = 0; i < 4; i++) {
                float4 a = *(const float4*)&xs[ng * 4 + i][k];
                fma4(acc[i], a.x, b0); fma4(acc[i], a.y, b1);
                fma4(acc[i], a.z, b2); fma4(acc[i], a.w, b3);
            }
        }
    }
    float4* h4 = (float4*)h;
    #pragma unroll
    for (int i = 0; i < 4; i++) {
        int gn = n0 + ng * 4 + i;
        if (gn < NN) {
            float dn = dinv[gn];
            float4 v = acc[i];
            v.x *= dn; v.y *= dn; v.z *= dn; v.w *= dn;
            h4[(size_t)gn * 16 + cg] = v;
        }
    }
}

// ---------------- fused CSR gather + finalize + next-layer 64x64 matmul ----------------
// Grid-stride persistent waves; W staged once per block. launch_bounds(256,6)
// allows the natural ~84 VGPR (512/6 = 85 cap, NO spills -- the (256,8)/64-cap
// build spilled 680 MB of scratch traffic, round 10). GB = 1536 = 6 blocks/CU
// so ALL blocks are resident in one shift (round 9's 2048-grid left 512
// stranded in a 25%-occupancy second shift).
__global__ void __launch_bounds__(256, 6) gather_mm_kernel(
    const int* __restrict__ col, const int* __restrict__ rowptr,
    const float* __restrict__ dinv, const float* __restrict__ h,
    const float* __restrict__ bias, const float* __restrict__ W,
    float* __restrict__ hout) {
    __shared__ float Wl[64][64];
    int t = threadIdx.x;
    {
        const float4* W4 = (const float4*)W;
        float4* wl4 = (float4*)&Wl[0][0];
        for (int i = t; i < 1024; i += 256) wl4[i] = W4[i];
    }
    __syncthreads();
    int l = t & 63;
    int g = l >> 4;      // edge sub-slot 0..3
    int q = l & 15;      // float4 slot 0..15
    const float4* h4 = (const float4*)h;
    int wid = (blockIdx.x * 256 + t) >> 6;      // global wave id
    const int nwave = (GB * 256) >> 6;          // 6144 waves
    for (int n = wid; n < NN; n += nwave) {
        float4 acc = make_float4(0, 0, 0, 0);
        int r0 = rowptr[n], r1 = rowptr[n + 1];
        for (int base = r0; base < r1; base += 64) {
            int cnt = min(64, r1 - base);
            int pv = NN;                          // sentinel: zero row
            if (l < cnt) pv = __builtin_nontemporal_load(col + base + l);
            int steps = (cnt + 3) >> 2;
            int j = 0;
            for (; j + 4 <= steps; j += 4) {
                int e0 = (j + 0) * 4 + g, e1 = (j + 1) * 4 + g;
                int e2 = (j + 2) * 4 + g, e3 = (j + 3) * 4 + g;
                int s0 = __shfl(pv, e0);
                int s1 = __shfl(pv, e1);
                int s2 = __shfl(pv, e2);
                int s3 = __shfl(pv, e3);
                float4 v0 = h4[(size_t)s0 * 16 + q];
                float4 v1 = h4[(size_t)s1 * 16 + q];
                float4 v2 = h4[(size_t)s2 * 16 + q];
                float4 v3 = h4[(size_t)s3 * 16 + q];
                add4(acc, v0); add4(acc, v1);
                add4(acc, v2); add4(acc, v3);
            }
            for (; j < steps; j++) {
                int e = j * 4 + g;
                int s = __shfl(pv, e);
                float4 v = h4[(size_t)s * 16 + q];
                add4(acc, v);
            }
        }
        acc.x += __shfl_xor(acc.x, 16); acc.y += __shfl_xor(acc.y, 16);
        acc.z += __shfl_xor(acc.z, 16); acc.w += __shfl_xor(acc.w, 16);
        acc.x += __shfl_xor(acc.x, 32); acc.y += __shfl_xor(acc.y, 32);
        acc.z += __shfl_xor(acc.z, 32); acc.w += __shfl_xor(acc.w, 32);
        // layer output r (all lanes; q-slot replicated)
        float dn = dinv[n];
        float4 hn = h4[(size_t)n * 16 + q];   // hs[n] = h[n]*dinv[n]
        float4 b4 = ((const float4*)bias)[q];
        float4 r;
        r.x = fmaxf(fmaf(dn, acc.x + hn.x, b4.x), 0.f);
        r.y = fmaxf(fmaf(dn, acc.y + hn.y, b4.y), 0.f);
        r.z = fmaxf(fmaf(dn, acc.z + hn.z, b4.z), 0.f);
        r.w = fmaxf(fmaf(dn, acc.w + hn.w, b4.w), 0.f);
        // next-layer matmul: lane l computes output column l
        float oc = 0.f;
        #pragma unroll
        for (int qq = 0; qq < 16; qq++) {
            float rx = __shfl(r.x, qq);
            float ry = __shfl(r.y, qq);
            float rz = __shfl(r.z, qq);
            float rw = __shfl(r.w, qq);
            oc = fmaf(rx, Wl[qq * 4 + 0][l], oc);
            oc = fmaf(ry, Wl[qq * 4 + 1][l], oc);
            oc = fmaf(rz, Wl[qq * 4 + 2][l], oc);
            oc = fmaf(rw, Wl[qq * 4 + 3][l], oc);
        }
        __builtin_nontemporal_store(oc * dn, &hout[(size_t)n * 64 + l]);
    }
}

// ---------------- fused CSR gather + finalize + output MLP ----------------
__global__ void __launch_bounds__(256, 6) gather_mlp_kernel(
    const int* __restrict__ col, const int* __restrict__ rowptr,
    const float* __restrict__ dinv, const float* __restrict__ h,
    const float* __restrict__ bias, const float* __restrict__ w1,
    const float* __restrict__ b1, const float* __restrict__ w2,
    const float* __restrict__ b2, float* __restrict__ out) {
    __shared__ float W1l[64][32];   // lane c reads W1l[k][c]: distinct banks
    __shared__ float w2l[32];
    __shared__ float b1l[32];
    int t = threadIdx.x;
    {
        const float4* w14 = (const float4*)w1;
        float4* wl4 = (float4*)&W1l[0][0];
        for (int i = t; i < 512; i += 256) wl4[i] = w14[i];
        if (t < 32) { w2l[t] = w2[t]; b1l[t] = b1[t]; }
    }
    __syncthreads();
    int l = t & 63;
    int g = l >> 4;
    int q = l & 15;
    const float4* h4 = (const float4*)h;
    int wid = (blockIdx.x * 256 + t) >> 6;
    const int nwave = (GB * 256) >> 6;
    for (int n = wid; n < NN; n += nwave) {
        float4 acc = make_float4(0, 0, 0, 0);
        int r0 = rowptr[n], r1 = rowptr[n + 1];
        for (int base = r0; base < r1; base += 64) {
            int cnt = min(64, r1 - base);
            int pv = NN;
            if (l < cnt) pv = __builtin_nontemporal_load(col + base + l);
            int steps = (cnt + 3) >> 2;
            int j = 0;
            for (; j + 4 <= steps; j += 4) {
                int e0 = (j + 0) * 4 + g, e1 = (j + 1) * 4 + g;
                int e2 = (j + 2) * 4 + g, e3 = (j + 3) * 4 + g;
                int s0 = __shfl(pv, e0);
                int s1 = __shfl(pv, e1);
                int s2 = __shfl(pv, e2);
                int s3 = __shfl(pv, e3);
                float4 v0 = h4[(size_t)s0 * 16 + q];
                float4 v1 = h4[(size_t)s1 * 16 + q];
                float4 v2 = h4[(size_t)s2 * 16 + q];
                float4 v3 = h4[(size_t)s3 * 16 + q];
                add4(acc, v0); add4(acc, v1);
                add4(acc, v2); add4(acc, v3);
            }
            for (; j < steps; j++) {
                int e = j * 4 + g;
                int s = __shfl(pv, e);
                float4 v = h4[(size_t)s * 16 + q];
                add4(acc, v);
            }
        }
        acc.x += __shfl_xor(acc.x, 16); acc.y += __shfl_xor(acc.y, 16);
        acc.z += __shfl_xor(acc.z, 16); acc.w += __shfl_xor(acc.w, 16);
        acc.x += __shfl_xor(acc.x, 32); acc.y += __shfl_xor(acc.y, 32);
        acc.z += __shfl_xor(acc.z, 32); acc.w += __shfl_xor(acc.w, 32);
        float dn = dinv[n];
        float4 hn = h4[(size_t)n * 16 + q];
        float4 b4 = ((const float4*)bias)[q];
        float4 r;
        r.x = fmaxf(fmaf(dn, acc.x + hn.x, b4.x), 0.f);
        r.y = fmaxf(fmaf(dn, acc.y + hn.y, b4.y), 0.f);
        r.z = fmaxf(fmaf(dn, acc.z + hn.z, b4.z), 0.f);
        r.w = fmaxf(fmaf(dn, acc.w + hn.w, b4.w), 0.f);
        // output MLP: hidden unit c = l&31
        int c = l & 31;
        float a2 = b1l[c];
        #pragma unroll
        for (int qq = 0; qq < 16; qq++) {
            float rx = __shfl(r.x, qq);
            float ry = __shfl(r.y, qq);
            float rz = __shfl(r.z, qq);
            float rw = __shfl(r.w, qq);
            a2 = fmaf(rx, W1l[qq * 4 + 0][c], a2);
            a2 = fmaf(ry, W1l[qq * 4 + 1][c], a2);
            a2 = fmaf(rz, W1l[qq * 4 + 2][c], a2);
            a2 = fmaf(rw, W1l[qq * 4 + 3][c], a2);
        }
        float v = fmaxf(a2, 0.f) * w2l[c];
        v += __shfl_xor(v, 1); v += __shfl_xor(v, 2);
        v += __shfl_xor(v, 4); v += __shfl_xor(v, 8);
        v += __shfl_xor(v, 16);
        if (l == 0) __builtin_nontemporal_store(v + b2[0], &out[n]);
    }
}

extern "C" void kernel_launch(void* const* d_in, const int* in_sizes, int n_in,
                              void* d_out, int out_size, void* d_ws, size_t ws_size,
                              hipStream_t stream) {
    const float* xf = (const float*)d_in[0];
    const float* xw = (const float*)d_in[1];
    const float* xt = (const float*)d_in[2];
    const int*   ei = (const int*)d_in[3];
    const int*   src = ei;
    const int*   dst = ei + NE;
    const float* Wf = (const float*)d_in[4];
    const float* bf = (const float*)d_in[5];
    const float* Ww = (const float*)d_in[6];
    const float* bw = (const float*)d_in[7];
    const float* Wt = (const float*)d_in[8];
    const float* bt = (const float*)d_in[9];
    const float* W0 = (const float*)d_in[10];
    const float* b0 = (const float*)d_in[11];
    const float* W1 = (const float*)d_in[12];
    const float* b1 = (const float*)d_in[13];
    const float* W2 = (const float*)d_in[14];
    const float* b2 = (const float*)d_in[15];
    const float* ow1 = (const float*)d_in[16];
    const float* ob1 = (const float*)d_in[17];
    const float* ow2 = (const float*)d_in[18];
    const float* ob2 = (const float*)d_in[19];
    float* out = (float*)d_out;

    // workspace layout. pairs (42 MB) ALIASES hA+hB: dead before encmm0 writes hA.
    char* w = (char*)d_ws;
    float* hA     = (float*)w;  w += (size_t)(NN + 1) * 64 * 4;      // 25.6 MB (+zero row)
    float* hB     = (float*)w;  w += (size_t)(NN + 1) * 64 * 4;      // 25.6 MB (+zero row)
    int*   col    = (int*)w;    w += (size_t)NE * 4;                 // 12.8 MB
    v2i*   povf   = (v2i*)w;    w += (size_t)NBUCK * OVFCAP * 8;     // 1 MB
    float* dinv   = (float*)w;  w += (size_t)NN * 4;
    int*   rowptr = (int*)w;    w += (size_t)(NN + 1) * 4;
    int*   bctl   = (int*)w;    w += (size_t)NBUCK * 16 * 4;         // 16 KB (padded lines)
    int*   bbase  = (int*)w;    w += (size_t)NBUCK * 4;
    v2i*   pairs  = (v2i*)hA;                                        // alias (42 MB <= 51.2 MB)

    // ---- CSR build (two-phase, line-staged; reused by all 3 layers) ----
    hipMemsetAsync(bctl, 0, (size_t)NBUCK * 16 * 4, stream);
    partition_kernel<<<P1_GRID, 256, 0, stream>>>(src, dst, bctl, pairs, povf);
    bucket_scan_kernel<<<1, NBUCK, 0, stream>>>(bctl, bbase, rowptr);
    csr_fill_kernel<<<NBUCK, 256, 0, stream>>>(pairs, povf, bctl, bbase, rowptr, dinv, col);
    // sentinel zero rows (after pairs is dead)
    hipMemsetAsync(hA + (size_t)NN * 64, 0, 64 * 4, stream);
    hipMemsetAsync(hB + (size_t)NN * 64, 0, 64 * 4, stream);

    // ---- layer 0: fused encoders + matmul (scaled) -> hA ----
    encmm0_kernel<<<(NN + 63) / 64, 256, 0, stream>>>(xf, xw, xt, Wf, bf, Ww, bw, Wt, bt, W0, dinv, hA);
    // ---- gather(b0) + mm(W1) : hA -> hB ----
    gather_mm_kernel<<<GB, 256, 0, stream>>>(col, rowptr, dinv, hA, b0, W1, hB);
    // ---- gather(b1) + mm(W2) : hB -> hA ----
    gather_mm_kernel<<<GB, 256, 0, stream>>>(col, rowptr, dinv, hB, b1, W2, hA);
    // ---- gather(b2) + output MLP : hA -> out ----
    gather_mlp_kernel<<<GB, 256, 0, stream>>>(col, rowptr, dinv, hA, b2, ow1, ob1, ow2, ob2, out);
}

// Round 12
// 625.854 us; speedup vs baseline: 1.9018x; 1.6472x over previous
//
#include <hip/hip_runtime.h>

#define NN 100000
#define NE 3200000
#define HD 64

// two-phase CSR build
#define NBUCK 256
#define BWID 392                                    // 256*392 = 100352 >= NN
#define SLACK 20480                                 // slots/bucket: 12544 real + ~5500 pad + margin
#define COLCAP 13568                                // real cols/bucket cap (12544 + ~9 sigma)
#define OVFCAP 512                                  // overflow pairs/bucket
#define CAP 16                                      // staged pairs per bucket per block
#define P1_EPB 2048                                 // edges per partition block
#define P1_GRID ((NE + P1_EPB - 1) / P1_EPB)        // 1563

typedef int   v4i __attribute__((ext_vector_type(4)));
typedef int   v2i __attribute__((ext_vector_type(2)));

__device__ __forceinline__ void fma4(float4& a, float s, const float4& b) {
    a.x = fmaf(s, b.x, a.x); a.y = fmaf(s, b.y, a.y);
    a.z = fmaf(s, b.z, a.z); a.w = fmaf(s, b.w, a.w);
}
__device__ __forceinline__ void add4(float4& a, const float4& b) {
    a.x += b.x; a.y += b.y; a.z += b.z; a.w += b.w;
}

// ---------------- phase 1: bucket partition, LDS-staged, 1 drain/block ----------------
__global__ void __launch_bounds__(256) partition_kernel(
    const int* __restrict__ src, const int* __restrict__ dst,
    int* __restrict__ bctl, v2i* __restrict__ pairs, v2i* __restrict__ povf) {
    __shared__ v2i stage[NBUCK][CAP];
    __shared__ int cnt[NBUCK];
    int t = threadIdx.x;
    cnt[t] = 0;                         // NBUCK == blockDim == 256
    __syncthreads();
    const v4i* d4p = (const v4i*)dst;
    const v4i* s4p = (const v4i*)src;
    const int NE4 = NE / 4;
    int base4 = blockIdx.x * (P1_EPB / 4);
    #pragma unroll
    for (int it = 0; it < P1_EPB / 1024; it++) {
        int i = base4 + it * 256 + t;
        v4i d4 = (v4i){-1, -1, -1, -1};
        v4i s4 = (v4i){0, 0, 0, 0};
        if (i < NE4) {
            d4 = __builtin_nontemporal_load(d4p + i);
            s4 = __builtin_nontemporal_load(s4p + i);
        }
        #pragma unroll
        for (int k = 0; k < 4; k++) {
            int d = d4[k];
            if (d >= 0) {
                int b = (unsigned)d / BWID;
                int slot = atomicAdd(&cnt[b], 1);
                v2i p; p[0] = s4[k]; p[1] = d;
                if (slot < CAP) {
                    stage[b][slot] = p;
                } else {                 // rare overflow -> separate region
                    int o = atomicAdd(&bctl[b * 16 + 2], 1);
                    if (o < OVFCAP) povf[(size_t)b * OVFCAP + o] = p;
                }
            }
        }
    }
    __syncthreads();
    // drain bucket t (single drain per block)
    int c_tot = cnt[t];
    int c = (c_tot > CAP) ? CAP : c_tot;
    int runs = (c + 7) >> 3;             // 0..2
    if (runs) {
        int slots = runs * 8;            // 8 or 16, <= CAP
        for (int m = c; m < slots; m++) { v2i p; p[0] = 0; p[1] = -1; stage[t][m] = p; }
        int gb = atomicAdd(&bctl[t * 16], slots);   // stays multiple of 8
        if (gb + slots <= SLACK) {
            v4i* gp = (v4i*)(pairs + (size_t)t * SLACK + gb);
            const v4i* sp = (const v4i*)&stage[t][0];
            #pragma unroll
            for (int m = 0; m < 8; m++) { if (m < runs * 4) gp[m] = sp[m]; }
        } else {
            for (int m = 0; m < slots && gb + m < SLACK; m++)
                pairs[(size_t)t * SLACK + gb + m] = stage[t][m];
        }
    }
    if (c_tot > 0) atomicAdd(&bctl[t * 16 + 1], c_tot);   // real contribution
}

// ---------------- tiny scan over real bucket counts ----------------
__global__ void bucket_scan_kernel(const int* __restrict__ bctl,
                                   int* __restrict__ bbase, int* __restrict__ rowptr) {
    __shared__ int s[NBUCK];
    int t = threadIdx.x;
    int v = bctl[t * 16 + 1];
    s[t] = v; __syncthreads();
    for (int off = 1; off < NBUCK; off <<= 1) {
        int x = (t >= off) ? s[t - off] : 0;
        __syncthreads();
        s[t] += x;
        __syncthreads();
    }
    bbase[t] = s[t] - v;                 // exclusive prefix of real counts
    if (t == NBUCK - 1) rowptr[NN] = s[t];   // == NE
}

// ---------------- phase 2: per-bucket hist + scan + LDS scatter ----------------
__global__ void __launch_bounds__(256) csr_fill_kernel(
    const v2i* __restrict__ pairs, const v2i* __restrict__ povf,
    const int* __restrict__ bctl, const int* __restrict__ bbase,
    int* __restrict__ rowptr, float* __restrict__ dinv, int* __restrict__ col) {
    __shared__ int hist[BWID];
    __shared__ int rp[BWID];
    __shared__ int cur[BWID];
    __shared__ int sc[256];
    __shared__ int cols[COLCAP];
    int b = blockIdx.x, t = threadIdx.x;
    int lo = b * BWID;
    int hi = min(lo + BWID, NN);
    int nw = hi - lo;
    for (int i = t; i < BWID; i += 256) { hist[i] = 0; cur[i] = 0; }
    __syncthreads();
    int np = bctl[b * 16];     if (np > SLACK) np = SLACK;
    int nov = bctl[b * 16 + 2]; if (nov > OVFCAP) nov = OVFCAP;
    int base = bbase[b];
    const v2i* pb = pairs + (size_t)b * SLACK;
    const v2i* ob = povf + (size_t)b * OVFCAP;
    // pass 1: histogram (skip sentinels)
    for (int i = t; i < np; i += 256) {
        v2i p = pb[i];
        if (p[1] >= 0) atomicAdd(&hist[p[1] - lo], 1);
    }
    for (int i = t; i < nov; i += 256) {
        v2i p = ob[i];
        atomicAdd(&hist[p[1] - lo], 1);
    }
    __syncthreads();
    // exclusive scan of hist -> rp (2 elements per thread)
    int h0 = 0, s2 = 0;
    if (2 * t < BWID) {
        h0 = hist[2 * t];
        int h1 = (2 * t + 1 < BWID) ? hist[2 * t + 1] : 0;
        s2 = h0 + h1;
    }
    sc[t] = s2; __syncthreads();
    for (int off = 1; off < 256; off <<= 1) {
        int x = (t >= off) ? sc[t - off] : 0;
        __syncthreads();
        sc[t] += x;
        __syncthreads();
    }
    if (2 * t < BWID) {
        int ex = sc[t] - s2;
        rp[2 * t] = ex;
        if (2 * t + 1 < BWID) rp[2 * t + 1] = ex + h0;
    }
    __syncthreads();
    // rowptr + dinv slices (coalesced)
    for (int i = t; i < nw; i += 256) {
        rowptr[lo + i] = base + rp[i];
        dinv[lo + i] = 1.0f / sqrtf((float)(hist[i] + 1));  // +1 self-loop
    }
    // pass 2: scatter into LDS
    for (int i = t; i < np; i += 256) {
        v2i p = pb[i];
        if (p[1] >= 0) {
            int li = p[1] - lo;
            int slot = atomicAdd(&cur[li], 1);
            int o = rp[li] + slot;
            if (o < COLCAP) cols[o] = p[0];
        }
    }
    for (int i = t; i < nov; i += 256) {
        v2i p = ob[i];
        int li = p[1] - lo;
        int slot = atomicAdd(&cur[li], 1);
        int o = rp[li] + slot;
        if (o < COLCAP) cols[o] = p[0];
    }
    __syncthreads();
    // contiguous col write (real count only)
    int nreal = bctl[b * 16 + 1]; if (nreal > COLCAP) nreal = COLCAP;
    for (int i = t; i < nreal; i += 256)
        col[base + i] = cols[i];
}

// ---------------- fused modality encoders + GCN layer-0 matmul ----------------
__global__ void __launch_bounds__(256) encmm0_kernel(
    const float* __restrict__ xf, const float* __restrict__ xw, const float* __restrict__ xt,
    const float* __restrict__ Wf, const float* __restrict__ bf,
    const float* __restrict__ Ww, const float* __restrict__ bw,
    const float* __restrict__ Wt, const float* __restrict__ bt,
    const float* __restrict__ W0, const float* __restrict__ dinv,
    float* __restrict__ h) {
    __shared__ float xin[64][32];    // fire[0..7], wea[8..19], ter[20..29]
    __shared__ float wenc[30][64];   // encoder weights (rows match xin cols)
    __shared__ float bs[192];        // encoder biases
    __shared__ float xs[64][36];     // encoder outputs for current 32-slice (+4 pad)
    __shared__ float ws[32][64];     // W0 rows for current slice
    int t = threadIdx.x;
    int n0 = blockIdx.x * 64;

    {   // stage raw inputs
        const float4* xf4 = (const float4*)xf;
        for (int i = t; i < 128; i += 256) {
            int n = i >> 1, q = i & 1;
            int gn = n0 + n;
            float4 v = make_float4(0, 0, 0, 0);
            if (gn < NN) v = xf4[(size_t)gn * 2 + q];
            *(float4*)&xin[n][q * 4] = v;
        }
        const float4* xw4 = (const float4*)xw;
        for (int i = t; i < 192; i += 256) {
            int n = i / 3, q = i - n * 3;
            int gn = n0 + n;
            float4 v = make_float4(0, 0, 0, 0);
            if (gn < NN) v = xw4[(size_t)gn * 3 + q];
            *(float4*)&xin[n][8 + q * 4] = v;
        }
        const float2* xt2 = (const float2*)xt;
        for (int i = t; i < 320; i += 256) {
            int n = i / 5, q = i - n * 5;
            int gn = n0 + n;
            float2 v = make_float2(0, 0);
            if (gn < NN) v = xt2[(size_t)gn * 5 + q];
            *(float2*)&xin[n][20 + q * 2] = v;
        }
        // stage encoder weights: rows 0-7 Wf, 8-19 Ww, 20-29 Wt
        for (int i = t; i < 480; i += 256) {
            int r = i >> 4, q = i & 15;
            float4 v;
            if (r < 8)       v = ((const float4*)Wf)[r * 16 + q];
            else if (r < 20) v = ((const float4*)Ww)[(r - 8) * 16 + q];
            else             v = ((const float4*)Wt)[(r - 20) * 16 + q];
            *(float4*)&wenc[r][q * 4] = v;
        }
        // stage encoder biases
        if (t < 192) bs[t] = (t < 64) ? bf[t] : (t < 128) ? bw[t - 64] : bt[t - 128];
    }

    int cg = t & 15, ng = t >> 4;
    int c0 = cg * 4;
    float4 acc[4];
    #pragma unroll
    for (int i = 0; i < 4; i++) acc[i] = make_float4(0, 0, 0, 0);

    for (int kq = 0; kq < 6; kq++) {
        __syncthreads();
        {   // stage W0 slice rows [kq*32, kq*32+32)
            const float4* W04 = (const float4*)W0;
            float4* ws4 = (float4*)&ws[0][0];
            for (int i = t; i < 512; i += 256)
                ws4[i] = W04[(size_t)kq * 512 + i];
        }
        // compute encoder outputs for this slice (uniform modality per kq)
        int coff = (kq < 2) ? kq * 32 : (kq < 4) ? (kq - 2) * 32 : (kq - 4) * 32;
        if (kq < 2) {
            for (int i = t; i < 2048; i += 256) {
                int n = i >> 5, kk = i & 31;
                float a = bs[kq * 32 + kk];
                #pragma unroll
                for (int k = 0; k < 8; k++) a = fmaf(xin[n][k], wenc[k][coff + kk], a);
                xs[n][kk] = fmaxf(a, 0.f);
            }
        } else if (kq < 4) {
            for (int i = t; i < 2048; i += 256) {
                int n = i >> 5, kk = i & 31;
                float a = bs[kq * 32 + kk];
                #pragma unroll
                for (int k = 0; k < 12; k++) a = fmaf(xin[n][8 + k], wenc[8 + k][coff + kk], a);
                xs[n][kk] = fmaxf(a, 0.f);
            }
        } else {
            for (int i = t; i < 2048; i += 256) {
                int n = i >> 5, kk = i & 31;
                float a = bs[kq * 32 + kk];
                #pragma unroll
                for (int k = 0; k < 10; k++) a = fmaf(xin[n][20 + k], wenc[20 + k][coff + kk], a);
                xs[n][kk] = fmaxf(a, 0.f);
            }
        }
        __syncthreads();
        // register-blocked fma over this 32-slice
        for (int k = 0; k < 32; k += 4) {
            float4 b0 = *(const float4*)&ws[k + 0][c0];
            float4 b1 = *(const float4*)&ws[k + 1][c0];
            float4 b2 = *(const float4*)&ws[k + 2][c0];
            float4 b3 = *(const float4*)&ws[k + 3][c0];
            #pragma unroll
            for (int i = 0; i < 4; i++) {
                float4 a = *(const float4*)&xs[ng * 4 + i][k];
                fma4(acc[i], a.x, b0); fma4(acc[i], a.y, b1);
                fma4(acc[i], a.z, b2); fma4(acc[i], a.w, b3);
            }
        }
    }
    float4* h4 = (float4*)h;
    #pragma unroll
    for (int i = 0; i < 4; i++) {
        int gn = n0 + ng * 4 + i;
        if (gn < NN) {
            float dn = dinv[gn];
            float4 v = acc[i];
            v.x *= dn; v.y *= dn; v.z *= dn; v.w *= dn;
            h4[(size_t)gn * 16 + cg] = v;
        }
    }
}

// ---------------- fused CSR gather + finalize + next-layer 64x64 matmul ----------------
// One node per wave via blockIdx (no loop -> naturally low VGPR, high occupancy;
// grid-stride/launch_bounds variants spilled or double-shifted -- rounds 9-11).
// NO LDS W staging: in the tail, lane l reads W[k*64+l] -- a coalesced row read
// of a 16 KB L1-resident matrix. No barrier, no staging serialization.
__global__ void gather_mm_kernel(
    const int* __restrict__ col, const int* __restrict__ rowptr,
    const float* __restrict__ dinv, const float* __restrict__ h,
    const float* __restrict__ bias, const float* __restrict__ W,
    float* __restrict__ hout) {
    int t = threadIdx.x;
    int n = (blockIdx.x * 256 + t) >> 6;
    int l = t & 63;
    if (n >= NN) return;
    int g = l >> 4;      // edge sub-slot 0..3
    int q = l & 15;      // float4 slot 0..15
    const float4* h4 = (const float4*)h;
    float4 acc = make_float4(0, 0, 0, 0);
    int r0 = rowptr[n], r1 = rowptr[n + 1];
    for (int base = r0; base < r1; base += 64) {
        int cnt = min(64, r1 - base);
        int pv = NN;                          // sentinel: zero row
        if (l < cnt) pv = __builtin_nontemporal_load(col + base + l);
        int steps = (cnt + 3) >> 2;
        int j = 0;
        for (; j + 4 <= steps; j += 4) {
            int e0 = (j + 0) * 4 + g, e1 = (j + 1) * 4 + g;
            int e2 = (j + 2) * 4 + g, e3 = (j + 3) * 4 + g;
            int s0 = __shfl(pv, e0);
            int s1 = __shfl(pv, e1);
            int s2 = __shfl(pv, e2);
            int s3 = __shfl(pv, e3);
            float4 v0 = h4[(size_t)s0 * 16 + q];
            float4 v1 = h4[(size_t)s1 * 16 + q];
            float4 v2 = h4[(size_t)s2 * 16 + q];
            float4 v3 = h4[(size_t)s3 * 16 + q];
            add4(acc, v0); add4(acc, v1);
            add4(acc, v2); add4(acc, v3);
        }
        for (; j < steps; j++) {
            int e = j * 4 + g;
            int s = __shfl(pv, e);
            float4 v = h4[(size_t)s * 16 + q];
            add4(acc, v);
        }
    }
    acc.x += __shfl_xor(acc.x, 16); acc.y += __shfl_xor(acc.y, 16);
    acc.z += __shfl_xor(acc.z, 16); acc.w += __shfl_xor(acc.w, 16);
    acc.x += __shfl_xor(acc.x, 32); acc.y += __shfl_xor(acc.y, 32);
    acc.z += __shfl_xor(acc.z, 32); acc.w += __shfl_xor(acc.w, 32);
    // layer output r (all lanes; q-slot replicated)
    float dn = dinv[n];
    float4 hn = h4[(size_t)n * 16 + q];   // hs[n] = h[n]*dinv[n]
    float4 b4 = ((const float4*)bias)[q];
    float4 r;
    r.x = fmaxf(fmaf(dn, acc.x + hn.x, b4.x), 0.f);
    r.y = fmaxf(fmaf(dn, acc.y + hn.y, b4.y), 0.f);
    r.z = fmaxf(fmaf(dn, acc.z + hn.z, b4.z), 0.f);
    r.w = fmaxf(fmaf(dn, acc.w + hn.w, b4.w), 0.f);
    // next-layer matmul: lane l computes output column l; W rows from L1
    // (4 partial accumulators break the fmaf dependency chain)
    float oc0 = 0.f, oc1 = 0.f, oc2 = 0.f, oc3 = 0.f;
    #pragma unroll
    for (int qq = 0; qq < 16; qq++) {
        float rx = __shfl(r.x, qq);
        float ry = __shfl(r.y, qq);
        float rz = __shfl(r.z, qq);
        float rw = __shfl(r.w, qq);
        oc0 = fmaf(rx, W[(qq * 4 + 0) * 64 + l], oc0);
        oc1 = fmaf(ry, W[(qq * 4 + 1) * 64 + l], oc1);
        oc2 = fmaf(rz, W[(qq * 4 + 2) * 64 + l], oc2);
        oc3 = fmaf(rw, W[(qq * 4 + 3) * 64 + l], oc3);
    }
    float oc = (oc0 + oc1) + (oc2 + oc3);
    __builtin_nontemporal_store(oc * dn, &hout[(size_t)n * 64 + l]);
}

// ---------------- fused CSR gather + finalize + output MLP ----------------
__global__ void gather_mlp_kernel(
    const int* __restrict__ col, const int* __restrict__ rowptr,
    const float* __restrict__ dinv, const float* __restrict__ h,
    const float* __restrict__ bias, const float* __restrict__ w1,
    const float* __restrict__ b1, const float* __restrict__ w2,
    const float* __restrict__ b2, float* __restrict__ out) {
    int t = threadIdx.x;
    int n = (blockIdx.x * 256 + t) >> 6;
    int l = t & 63;
    if (n >= NN) return;
    int g = l >> 4;
    int q = l & 15;
    const float4* h4 = (const float4*)h;
    float4 acc = make_float4(0, 0, 0, 0);
    int r0 = rowptr[n], r1 = rowptr[n + 1];
    for (int base = r0; base < r1; base += 64) {
        int cnt = min(64, r1 - base);
        int pv = NN;
        if (l < cnt) pv = __builtin_nontemporal_load(col + base + l);
        int steps = (cnt + 3) >> 2;
        int j = 0;
        for (; j + 4 <= steps; j += 4) {
            int e0 = (j + 0) * 4 + g, e1 = (j + 1) * 4 + g;
            int e2 = (j + 2) * 4 + g, e3 = (j + 3) * 4 + g;
            int s0 = __shfl(pv, e0);
            int s1 = __shfl(pv, e1);
            int s2 = __shfl(pv, e2);
            int s3 = __shfl(pv, e3);
            float4 v0 = h4[(size_t)s0 * 16 + q];
            float4 v1 = h4[(size_t)s1 * 16 + q];
            float4 v2 = h4[(size_t)s2 * 16 + q];
            float4 v3 = h4[(size_t)s3 * 16 + q];
            add4(acc, v0); add4(acc, v1);
            add4(acc, v2); add4(acc, v3);
        }
        for (; j < steps; j++) {
            int e = j * 4 + g;
            int s = __shfl(pv, e);
            float4 v = h4[(size_t)s * 16 + q];
            add4(acc, v);
        }
    }
    acc.x += __shfl_xor(acc.x, 16); acc.y += __shfl_xor(acc.y, 16);
    acc.z += __shfl_xor(acc.z, 16); acc.w += __shfl_xor(acc.w, 16);
    acc.x += __shfl_xor(acc.x, 32); acc.y += __shfl_xor(acc.y, 32);
    acc.z += __shfl_xor(acc.z, 32); acc.w += __shfl_xor(acc.w, 32);
    float dn = dinv[n];
    float4 hn = h4[(size_t)n * 16 + q];
    float4 b4 = ((const float4*)bias)[q];
    float4 r;
    r.x = fmaxf(fmaf(dn, acc.x + hn.x, b4.x), 0.f);
    r.y = fmaxf(fmaf(dn, acc.y + hn.y, b4.y), 0.f);
    r.z = fmaxf(fmaf(dn, acc.z + hn.z, b4.z), 0.f);
    r.w = fmaxf(fmaf(dn, acc.w + hn.w, b4.w), 0.f);
    // output MLP: hidden unit c = l&31 (w1 rows are L1-resident, coalesced)
    int c = l & 31;
    float a0 = b1[c], a1 = 0.f, a2p = 0.f, a3 = 0.f;
    #pragma unroll
    for (int qq = 0; qq < 16; qq++) {
        float rx = __shfl(r.x, qq);
        float ry = __shfl(r.y, qq);
        float rz = __shfl(r.z, qq);
        float rw = __shfl(r.w, qq);
        a0  = fmaf(rx, w1[(qq * 4 + 0) * 32 + c], a0);
        a1  = fmaf(ry, w1[(qq * 4 + 1) * 32 + c], a1);
        a2p = fmaf(rz, w1[(qq * 4 + 2) * 32 + c], a2p);
        a3  = fmaf(rw, w1[(qq * 4 + 3) * 32 + c], a3);
    }
    float a = (a0 + a1) + (a2p + a3);
    float v = fmaxf(a, 0.f) * w2[c];
    v += __shfl_xor(v, 1); v += __shfl_xor(v, 2);
    v += __shfl_xor(v, 4); v += __shfl_xor(v, 8);
    v += __shfl_xor(v, 16);
    if (l == 0) __builtin_nontemporal_store(v + b2[0], &out[n]);
}

extern "C" void kernel_launch(void* const* d_in, const int* in_sizes, int n_in,
                              void* d_out, int out_size, void* d_ws, size_t ws_size,
                              hipStream_t stream) {
    const float* xf = (const float*)d_in[0];
    const float* xw = (const float*)d_in[1];
    const float* xt = (const float*)d_in[2];
    const int*   ei = (const int*)d_in[3];
    const int*   src = ei;
    const int*   dst = ei + NE;
    const float* Wf = (const float*)d_in[4];
    const float* bf = (const float*)d_in[5];
    const float* Ww = (const float*)d_in[6];
    const float* bw = (const float*)d_in[7];
    const float* Wt = (const float*)d_in[8];
    const float* bt = (const float*)d_in[9];
    const float* W0 = (const float*)d_in[10];
    const float* b0 = (const float*)d_in[11];
    const float* W1 = (const float*)d_in[12];
    const float* b1 = (const float*)d_in[13];
    const float* W2 = (const float*)d_in[14];
    const float* b2 = (const float*)d_in[15];
    const float* ow1 = (const float*)d_in[16];
    const float* ob1 = (const float*)d_in[17];
    const float* ow2 = (const float*)d_in[18];
    const float* ob2 = (const float*)d_in[19];
    float* out = (float*)d_out;

    // workspace layout. pairs (42 MB) ALIASES hA+hB: dead before encmm0 writes hA.
    char* w = (char*)d_ws;
    float* hA     = (float*)w;  w += (size_t)(NN + 1) * 64 * 4;      // 25.6 MB (+zero row)
    float* hB     = (float*)w;  w += (size_t)(NN + 1) * 64 * 4;      // 25.6 MB (+zero row)
    int*   col    = (int*)w;    w += (size_t)NE * 4;                 // 12.8 MB
    v2i*   povf   = (v2i*)w;    w += (size_t)NBUCK * OVFCAP * 8;     // 1 MB
    float* dinv   = (float*)w;  w += (size_t)NN * 4;
    int*   rowptr = (int*)w;    w += (size_t)(NN + 1) * 4;
    int*   bctl   = (int*)w;    w += (size_t)NBUCK * 16 * 4;         // 16 KB (padded lines)
    int*   bbase  = (int*)w;    w += (size_t)NBUCK * 4;
    v2i*   pairs  = (v2i*)hA;                                        // alias (42 MB <= 51.2 MB)

    // ---- CSR build (two-phase, line-staged; reused by all 3 layers) ----
    hipMemsetAsync(bctl, 0, (size_t)NBUCK * 16 * 4, stream);
    partition_kernel<<<P1_GRID, 256, 0, stream>>>(src, dst, bctl, pairs, povf);
    bucket_scan_kernel<<<1, NBUCK, 0, stream>>>(bctl, bbase, rowptr);
    csr_fill_kernel<<<NBUCK, 256, 0, stream>>>(pairs, povf, bctl, bbase, rowptr, dinv, col);
    // sentinel zero rows (after pairs is dead)
    hipMemsetAsync(hA + (size_t)NN * 64, 0, 64 * 4, stream);
    hipMemsetAsync(hB + (size_t)NN * 64, 0, 64 * 4, stream);

    // ---- layer 0: fused encoders + matmul (scaled) -> hA ----
    encmm0_kernel<<<(NN + 63) / 64, 256, 0, stream>>>(xf, xw, xt, Wf, bf, Ww, bw, Wt, bt, W0, dinv, hA);
    // ---- gather(b0) + mm(W1) : hA -> hB ----
    gather_mm_kernel<<<(NN * 64 + 255) / 256, 256, 0, stream>>>(col, rowptr, dinv, hA, b0, W1, hB);
    // ---- gather(b1) + mm(W2) : hB -> hA ----
    gather_mm_kernel<<<(NN * 64 + 255) / 256, 256, 0, stream>>>(col, rowptr, dinv, hB, b1, W2, hA);
    // ---- gather(b2) + output MLP : hA -> out ----
    gather_mlp_kernel<<<(NN * 64 + 255) / 256, 256, 0, stream>>>(col, rowptr, dinv, hA, b2, ow1, ob1, ow2, ob2, out);
}

// Round 13
// 576.707 us; speedup vs baseline: 2.0639x; 1.0852x over previous
//
#include <hip/hip_runtime.h>

#define NN 100000
#define NE 3200000
#define HD 64

// two-phase CSR build
#define NBUCK 256
#define BWID 392                                    // 256*392 = 100352 >= NN
#define SLACK 20480                                 // slots/bucket: 12544 real + ~5500 pad + margin
#define COLCAP 13568                                // real cols/bucket cap (12544 + ~9 sigma)
#define OVFCAP 512                                  // overflow pairs/bucket
#define CAP 16                                      // staged pairs per bucket per block
#define P1_EPB 2048                                 // edges per partition block
#define P1_GRID ((NE + P1_EPB - 1) / P1_EPB)        // 1563

typedef int      v4i __attribute__((ext_vector_type(4)));
typedef int      v2i __attribute__((ext_vector_type(2)));
typedef _Float16 h4f __attribute__((ext_vector_type(4)));   // 4 halves = 8 B

__device__ __forceinline__ void fma4(float4& a, float s, const float4& b) {
    a.x = fmaf(s, b.x, a.x); a.y = fmaf(s, b.y, a.y);
    a.z = fmaf(s, b.z, a.z); a.w = fmaf(s, b.w, a.w);
}
__device__ __forceinline__ void addh4(float4& a, const h4f& b) {
    a.x += (float)b[0]; a.y += (float)b[1]; a.z += (float)b[2]; a.w += (float)b[3];
}

// ---------------- phase 1: bucket partition, LDS-staged, 1 drain/block ----------------
__global__ void __launch_bounds__(256) partition_kernel(
    const int* __restrict__ src, const int* __restrict__ dst,
    int* __restrict__ bctl, v2i* __restrict__ pairs, v2i* __restrict__ povf) {
    __shared__ v2i stage[NBUCK][CAP];
    __shared__ int cnt[NBUCK];
    int t = threadIdx.x;
    cnt[t] = 0;                         // NBUCK == blockDim == 256
    __syncthreads();
    const v4i* d4p = (const v4i*)dst;
    const v4i* s4p = (const v4i*)src;
    const int NE4 = NE / 4;
    int base4 = blockIdx.x * (P1_EPB / 4);
    #pragma unroll
    for (int it = 0; it < P1_EPB / 1024; it++) {
        int i = base4 + it * 256 + t;
        v4i d4 = (v4i){-1, -1, -1, -1};
        v4i s4 = (v4i){0, 0, 0, 0};
        if (i < NE4) {
            d4 = __builtin_nontemporal_load(d4p + i);
            s4 = __builtin_nontemporal_load(s4p + i);
        }
        #pragma unroll
        for (int k = 0; k < 4; k++) {
            int d = d4[k];
            if (d >= 0) {
                int b = (unsigned)d / BWID;
                int slot = atomicAdd(&cnt[b], 1);
                v2i p; p[0] = s4[k]; p[1] = d;
                if (slot < CAP) {
                    stage[b][slot] = p;
                } else {                 // rare overflow -> separate region
                    int o = atomicAdd(&bctl[b * 16 + 2], 1);
                    if (o < OVFCAP) povf[(size_t)b * OVFCAP + o] = p;
                }
            }
        }
    }
    __syncthreads();
    // drain bucket t (single drain per block)
    int c_tot = cnt[t];
    int c = (c_tot > CAP) ? CAP : c_tot;
    int runs = (c + 7) >> 3;             // 0..2
    if (runs) {
        int slots = runs * 8;            // 8 or 16, <= CAP
        for (int m = c; m < slots; m++) { v2i p; p[0] = 0; p[1] = -1; stage[t][m] = p; }
        int gb = atomicAdd(&bctl[t * 16], slots);   // stays multiple of 8
        if (gb + slots <= SLACK) {
            v4i* gp = (v4i*)(pairs + (size_t)t * SLACK + gb);
            const v4i* sp = (const v4i*)&stage[t][0];
            #pragma unroll
            for (int m = 0; m < 8; m++) { if (m < runs * 4) gp[m] = sp[m]; }
        } else {
            for (int m = 0; m < slots && gb + m < SLACK; m++)
                pairs[(size_t)t * SLACK + gb + m] = stage[t][m];
        }
    }
    if (c_tot > 0) atomicAdd(&bctl[t * 16 + 1], c_tot);   // real contribution
}

// ---------------- tiny scan over real bucket counts ----------------
__global__ void bucket_scan_kernel(const int* __restrict__ bctl,
                                   int* __restrict__ bbase, int* __restrict__ rowptr) {
    __shared__ int s[NBUCK];
    int t = threadIdx.x;
    int v = bctl[t * 16 + 1];
    s[t] = v; __syncthreads();
    for (int off = 1; off < NBUCK; off <<= 1) {
        int x = (t >= off) ? s[t - off] : 0;
        __syncthreads();
        s[t] += x;
        __syncthreads();
    }
    bbase[t] = s[t] - v;                 // exclusive prefix of real counts
    if (t == NBUCK - 1) rowptr[NN] = s[t];   // == NE
}

// ---------------- phase 2: per-bucket hist + scan + LDS scatter ----------------
__global__ void __launch_bounds__(256) csr_fill_kernel(
    const v2i* __restrict__ pairs, const v2i* __restrict__ povf,
    const int* __restrict__ bctl, const int* __restrict__ bbase,
    int* __restrict__ rowptr, float* __restrict__ dinv, int* __restrict__ col) {
    __shared__ int hist[BWID];
    __shared__ int rp[BWID];
    __shared__ int cur[BWID];
    __shared__ int sc[256];
    __shared__ int cols[COLCAP];
    int b = blockIdx.x, t = threadIdx.x;
    int lo = b * BWID;
    int hi = min(lo + BWID, NN);
    int nw = hi - lo;
    for (int i = t; i < BWID; i += 256) { hist[i] = 0; cur[i] = 0; }
    __syncthreads();
    int np = bctl[b * 16];     if (np > SLACK) np = SLACK;
    int nov = bctl[b * 16 + 2]; if (nov > OVFCAP) nov = OVFCAP;
    int base = bbase[b];
    const v2i* pb = pairs + (size_t)b * SLACK;
    const v2i* ob = povf + (size_t)b * OVFCAP;
    // pass 1: histogram (skip sentinels)
    for (int i = t; i < np; i += 256) {
        v2i p = pb[i];
        if (p[1] >= 0) atomicAdd(&hist[p[1] - lo], 1);
    }
    for (int i = t; i < nov; i += 256) {
        v2i p = ob[i];
        atomicAdd(&hist[p[1] - lo], 1);
    }
    __syncthreads();
    // exclusive scan of hist -> rp (2 elements per thread)
    int h0 = 0, s2 = 0;
    if (2 * t < BWID) {
        h0 = hist[2 * t];
        int h1 = (2 * t + 1 < BWID) ? hist[2 * t + 1] : 0;
        s2 = h0 + h1;
    }
    sc[t] = s2; __syncthreads();
    for (int off = 1; off < 256; off <<= 1) {
        int x = (t >= off) ? sc[t - off] : 0;
        __syncthreads();
        sc[t] += x;
        __syncthreads();
    }
    if (2 * t < BWID) {
        int ex = sc[t] - s2;
        rp[2 * t] = ex;
        if (2 * t + 1 < BWID) rp[2 * t + 1] = ex + h0;
    }
    __syncthreads();
    // rowptr + dinv slices (coalesced)
    for (int i = t; i < nw; i += 256) {
        rowptr[lo + i] = base + rp[i];
        dinv[lo + i] = 1.0f / sqrtf((float)(hist[i] + 1));  // +1 self-loop
    }
    // pass 2: scatter into LDS
    for (int i = t; i < np; i += 256) {
        v2i p = pb[i];
        if (p[1] >= 0) {
            int li = p[1] - lo;
            int slot = atomicAdd(&cur[li], 1);
            int o = rp[li] + slot;
            if (o < COLCAP) cols[o] = p[0];
        }
    }
    for (int i = t; i < nov; i += 256) {
        v2i p = ob[i];
        int li = p[1] - lo;
        int slot = atomicAdd(&cur[li], 1);
        int o = rp[li] + slot;
        if (o < COLCAP) cols[o] = p[0];
    }
    __syncthreads();
    // contiguous col write (real count only)
    int nreal = bctl[b * 16 + 1]; if (nreal > COLCAP) nreal = COLCAP;
    for (int i = t; i < nreal; i += 256)
        col[base + i] = cols[i];
}

// ---------------- fused modality encoders + GCN layer-0 matmul ----------------
// Computes in fp32, stores hs = h*dinv as FP16 (halves gather traffic; compute
// precision unchanged, storage relative error 2.4e-4 on values ~0.05).
__global__ void __launch_bounds__(256) encmm0_kernel(
    const float* __restrict__ xf, const float* __restrict__ xw, const float* __restrict__ xt,
    const float* __restrict__ Wf, const float* __restrict__ bf,
    const float* __restrict__ Ww, const float* __restrict__ bw,
    const float* __restrict__ Wt, const float* __restrict__ bt,
    const float* __restrict__ W0, const float* __restrict__ dinv,
    _Float16* __restrict__ h) {
    __shared__ float xin[64][32];    // fire[0..7], wea[8..19], ter[20..29]
    __shared__ float wenc[30][64];   // encoder weights (rows match xin cols)
    __shared__ float bs[192];        // encoder biases
    __shared__ float xs[64][36];     // encoder outputs for current 32-slice (+4 pad)
    __shared__ float ws[32][64];     // W0 rows for current slice
    int t = threadIdx.x;
    int n0 = blockIdx.x * 64;

    {   // stage raw inputs
        const float4* xf4 = (const float4*)xf;
        for (int i = t; i < 128; i += 256) {
            int n = i >> 1, q = i & 1;
            int gn = n0 + n;
            float4 v = make_float4(0, 0, 0, 0);
            if (gn < NN) v = xf4[(size_t)gn * 2 + q];
            *(float4*)&xin[n][q * 4] = v;
        }
        const float4* xw4 = (const float4*)xw;
        for (int i = t; i < 192; i += 256) {
            int n = i / 3, q = i - n * 3;
            int gn = n0 + n;
            float4 v = make_float4(0, 0, 0, 0);
            if (gn < NN) v = xw4[(size_t)gn * 3 + q];
            *(float4*)&xin[n][8 + q * 4] = v;
        }
        const float2* xt2 = (const float2*)xt;
        for (int i = t; i < 320; i += 256) {
            int n = i / 5, q = i - n * 5;
            int gn = n0 + n;
            float2 v = make_float2(0, 0);
            if (gn < NN) v = xt2[(size_t)gn * 5 + q];
            *(float2*)&xin[n][20 + q * 2] = v;
        }
        // stage encoder weights: rows 0-7 Wf, 8-19 Ww, 20-29 Wt
        for (int i = t; i < 480; i += 256) {
            int r = i >> 4, q = i & 15;
            float4 v;
            if (r < 8)       v = ((const float4*)Wf)[r * 16 + q];
            else if (r < 20) v = ((const float4*)Ww)[(r - 8) * 16 + q];
            else             v = ((const float4*)Wt)[(r - 20) * 16 + q];
            *(float4*)&wenc[r][q * 4] = v;
        }
        // stage encoder biases
        if (t < 192) bs[t] = (t < 64) ? bf[t] : (t < 128) ? bw[t - 64] : bt[t - 128];
    }

    int cg = t & 15, ng = t >> 4;
    int c0 = cg * 4;
    float4 acc[4];
    #pragma unroll
    for (int i = 0; i < 4; i++) acc[i] = make_float4(0, 0, 0, 0);

    for (int kq = 0; kq < 6; kq++) {
        __syncthreads();
        {   // stage W0 slice rows [kq*32, kq*32+32)
            const float4* W04 = (const float4*)W0;
            float4* ws4 = (float4*)&ws[0][0];
            for (int i = t; i < 512; i += 256)
                ws4[i] = W04[(size_t)kq * 512 + i];
        }
        // compute encoder outputs for this slice (uniform modality per kq)
        int coff = (kq < 2) ? kq * 32 : (kq < 4) ? (kq - 2) * 32 : (kq - 4) * 32;
        if (kq < 2) {
            for (int i = t; i < 2048; i += 256) {
                int n = i >> 5, kk = i & 31;
                float a = bs[kq * 32 + kk];
                #pragma unroll
                for (int k = 0; k < 8; k++) a = fmaf(xin[n][k], wenc[k][coff + kk], a);
                xs[n][kk] = fmaxf(a, 0.f);
            }
        } else if (kq < 4) {
            for (int i = t; i < 2048; i += 256) {
                int n = i >> 5, kk = i & 31;
                float a = bs[kq * 32 + kk];
                #pragma unroll
                for (int k = 0; k < 12; k++) a = fmaf(xin[n][8 + k], wenc[8 + k][coff + kk], a);
                xs[n][kk] = fmaxf(a, 0.f);
            }
        } else {
            for (int i = t; i < 2048; i += 256) {
                int n = i >> 5, kk = i & 31;
                float a = bs[kq * 32 + kk];
                #pragma unroll
                for (int k = 0; k < 10; k++) a = fmaf(xin[n][20 + k], wenc[20 + k][coff + kk], a);
                xs[n][kk] = fmaxf(a, 0.f);
            }
        }
        __syncthreads();
        // register-blocked fma over this 32-slice
        for (int k = 0; k < 32; k += 4) {
            float4 b0 = *(const float4*)&ws[k + 0][c0];
            float4 b1 = *(const float4*)&ws[k + 1][c0];
            float4 b2 = *(const float4*)&ws[k + 2][c0];
            float4 b3 = *(const float4*)&ws[k + 3][c0];
            #pragma unroll
            for (int i = 0; i < 4; i++) {
                float4 a = *(const float4*)&xs[ng * 4 + i][k];
                fma4(acc[i], a.x, b0); fma4(acc[i], a.y, b1);
                fma4(acc[i], a.z, b2); fma4(acc[i], a.w, b3);
            }
        }
    }
    h4f* h4 = (h4f*)h;
    #pragma unroll
    for (int i = 0; i < 4; i++) {
        int gn = n0 + ng * 4 + i;
        if (gn < NN) {
            float dn = dinv[gn];
            h4f v;
            v[0] = (_Float16)(acc[i].x * dn);
            v[1] = (_Float16)(acc[i].y * dn);
            v[2] = (_Float16)(acc[i].z * dn);
            v[3] = (_Float16)(acc[i].w * dn);
            h4[(size_t)gn * 16 + cg] = v;
        }
    }
}

// ---------------- fused CSR gather + finalize + next-layer 64x64 matmul ----------------
// One node per wave via blockIdx; h rows stored FP16 (128 B/row -> halves the
// gather's fabric traffic AND doubles L2 residency of the 12.8 MB table).
// Accumulation and matmul stay fp32. W rows read from L1 (coalesced, resident).
__global__ void gather_mm_kernel(
    const int* __restrict__ col, const int* __restrict__ rowptr,
    const float* __restrict__ dinv, const _Float16* __restrict__ h,
    const float* __restrict__ bias, const float* __restrict__ W,
    _Float16* __restrict__ hout) {
    int t = threadIdx.x;
    int n = (blockIdx.x * 256 + t) >> 6;
    int l = t & 63;
    if (n >= NN) return;
    int g = l >> 4;      // edge sub-slot 0..3
    int q = l & 15;      // half4 slot 0..15
    const h4f* h4 = (const h4f*)h;
    float4 acc = make_float4(0, 0, 0, 0);
    int r0 = rowptr[n], r1 = rowptr[n + 1];
    for (int base = r0; base < r1; base += 64) {
        int cnt = min(64, r1 - base);
        int pv = NN;                          // sentinel: zero row
        if (l < cnt) pv = __builtin_nontemporal_load(col + base + l);
        int steps = (cnt + 3) >> 2;
        int j = 0;
        for (; j + 4 <= steps; j += 4) {
            int e0 = (j + 0) * 4 + g, e1 = (j + 1) * 4 + g;
            int e2 = (j + 2) * 4 + g, e3 = (j + 3) * 4 + g;
            int s0 = __shfl(pv, e0);
            int s1 = __shfl(pv, e1);
            int s2 = __shfl(pv, e2);
            int s3 = __shfl(pv, e3);
            h4f v0 = h4[(size_t)s0 * 16 + q];
            h4f v1 = h4[(size_t)s1 * 16 + q];
            h4f v2 = h4[(size_t)s2 * 16 + q];
            h4f v3 = h4[(size_t)s3 * 16 + q];
            addh4(acc, v0); addh4(acc, v1);
            addh4(acc, v2); addh4(acc, v3);
        }
        for (; j < steps; j++) {
            int e = j * 4 + g;
            int s = __shfl(pv, e);
            h4f v = h4[(size_t)s * 16 + q];
            addh4(acc, v);
        }
    }
    acc.x += __shfl_xor(acc.x, 16); acc.y += __shfl_xor(acc.y, 16);
    acc.z += __shfl_xor(acc.z, 16); acc.w += __shfl_xor(acc.w, 16);
    acc.x += __shfl_xor(acc.x, 32); acc.y += __shfl_xor(acc.y, 32);
    acc.z += __shfl_xor(acc.z, 32); acc.w += __shfl_xor(acc.w, 32);
    // layer output r (all lanes; q-slot replicated)
    float dn = dinv[n];
    h4f hnh = h4[(size_t)n * 16 + q];     // hs[n] = h[n]*dinv[n]
    float4 b4 = ((const float4*)bias)[q];
    float4 r;
    r.x = fmaxf(fmaf(dn, acc.x + (float)hnh[0], b4.x), 0.f);
    r.y = fmaxf(fmaf(dn, acc.y + (float)hnh[1], b4.y), 0.f);
    r.z = fmaxf(fmaf(dn, acc.z + (float)hnh[2], b4.z), 0.f);
    r.w = fmaxf(fmaf(dn, acc.w + (float)hnh[3], b4.w), 0.f);
    // next-layer matmul: lane l computes output column l; W rows from L1
    float oc0 = 0.f, oc1 = 0.f, oc2 = 0.f, oc3 = 0.f;
    #pragma unroll
    for (int qq = 0; qq < 16; qq++) {
        float rx = __shfl(r.x, qq);
        float ry = __shfl(r.y, qq);
        float rz = __shfl(r.z, qq);
        float rw = __shfl(r.w, qq);
        oc0 = fmaf(rx, W[(qq * 4 + 0) * 64 + l], oc0);
        oc1 = fmaf(ry, W[(qq * 4 + 1) * 64 + l], oc1);
        oc2 = fmaf(rz, W[(qq * 4 + 2) * 64 + l], oc2);
        oc3 = fmaf(rw, W[(qq * 4 + 3) * 64 + l], oc3);
    }
    float oc = (oc0 + oc1) + (oc2 + oc3);
    __builtin_nontemporal_store((_Float16)(oc * dn), &hout[(size_t)n * 64 + l]);
}

// ---------------- fused CSR gather + finalize + output MLP ----------------
__global__ void gather_mlp_kernel(
    const int* __restrict__ col, const int* __restrict__ rowptr,
    const float* __restrict__ dinv, const _Float16* __restrict__ h,
    const float* __restrict__ bias, const float* __restrict__ w1,
    const float* __restrict__ b1, const float* __restrict__ w2,
    const float* __restrict__ b2, float* __restrict__ out) {
    int t = threadIdx.x;
    int n = (blockIdx.x * 256 + t) >> 6;
    int l = t & 63;
    if (n >= NN) return;
    int g = l >> 4;
    int q = l & 15;
    const h4f* h4 = (const h4f*)h;
    float4 acc = make_float4(0, 0, 0, 0);
    int r0 = rowptr[n], r1 = rowptr[n + 1];
    for (int base = r0; base < r1; base += 64) {
        int cnt = min(64, r1 - base);
        int pv = NN;
        if (l < cnt) pv = __builtin_nontemporal_load(col + base + l);
        int steps = (cnt + 3) >> 2;
        int j = 0;
        for (; j + 4 <= steps; j += 4) {
            int e0 = (j + 0) * 4 + g, e1 = (j + 1) * 4 + g;
            int e2 = (j + 2) * 4 + g, e3 = (j + 3) * 4 + g;
            int s0 = __shfl(pv, e0);
            int s1 = __shfl(pv, e1);
            int s2 = __shfl(pv, e2);
            int s3 = __shfl(pv, e3);
            h4f v0 = h4[(size_t)s0 * 16 + q];
            h4f v1 = h4[(size_t)s1 * 16 + q];
            h4f v2 = h4[(size_t)s2 * 16 + q];
            h4f v3 = h4[(size_t)s3 * 16 + q];
            addh4(acc, v0); addh4(acc, v1);
            addh4(acc, v2); addh4(acc, v3);
        }
        for (; j < steps; j++) {
            int e = j * 4 + g;
            int s = __shfl(pv, e);
            h4f v = h4[(size_t)s * 16 + q];
            addh4(acc, v);
        }
    }
    acc.x += __shfl_xor(acc.x, 16); acc.y += __shfl_xor(acc.y, 16);
    acc.z += __shfl_xor(acc.z, 16); acc.w += __shfl_xor(acc.w, 16);
    acc.x += __shfl_xor(acc.x, 32); acc.y += __shfl_xor(acc.y, 32);
    acc.z += __shfl_xor(acc.z, 32); acc.w += __shfl_xor(acc.w, 32);
    float dn = dinv[n];
    h4f hnh = h4[(size_t)n * 16 + q];
    float4 b4 = ((const float4*)bias)[q];
    float4 r;
    r.x = fmaxf(fmaf(dn, acc.x + (float)hnh[0], b4.x), 0.f);
    r.y = fmaxf(fmaf(dn, acc.y + (float)hnh[1], b4.y), 0.f);
    r.z = fmaxf(fmaf(dn, acc.z + (float)hnh[2], b4.z), 0.f);
    r.w = fmaxf(fmaf(dn, acc.w + (float)hnh[3], b4.w), 0.f);
    // output MLP: hidden unit c = l&31 (w1 rows are L1-resident, coalesced)
    int c = l & 31;
    float a0 = b1[c], a1 = 0.f, a2p = 0.f, a3 = 0.f;
    #pragma unroll
    for (int qq = 0; qq < 16; qq++) {
        float rx = __shfl(r.x, qq);
        float ry = __shfl(r.y, qq);
        float rz = __shfl(r.z, qq);
        float rw = __shfl(r.w, qq);
        a0  = fmaf(rx, w1[(qq * 4 + 0) * 32 + c], a0);
        a1  = fmaf(ry, w1[(qq * 4 + 1) * 32 + c], a1);
        a2p = fmaf(rz, w1[(qq * 4 + 2) * 32 + c], a2p);
        a3  = fmaf(rw, w1[(qq * 4 + 3) * 32 + c], a3);
    }
    float a = (a0 + a1) + (a2p + a3);
    float v = fmaxf(a, 0.f) * w2[c];
    v += __shfl_xor(v, 1); v += __shfl_xor(v, 2);
    v += __shfl_xor(v, 4); v += __shfl_xor(v, 8);
    v += __shfl_xor(v, 16);
    if (l == 0) __builtin_nontemporal_store(v + b2[0], &out[n]);
}

extern "C" void kernel_launch(void* const* d_in, const int* in_sizes, int n_in,
                              void* d_out, int out_size, void* d_ws, size_t ws_size,
                              hipStream_t stream) {
    const float* xf = (const float*)d_in[0];
    const float* xw = (const float*)d_in[1];
    const float* xt = (const float*)d_in[2];
    const int*   ei = (const int*)d_in[3];
    const int*   src = ei;
    const int*   dst = ei + NE;
    const float* Wf = (const float*)d_in[4];
    const float* bf = (const float*)d_in[5];
    const float* Ww = (const float*)d_in[6];
    const float* bw = (const float*)d_in[7];
    const float* Wt = (const float*)d_in[8];
    const float* bt = (const float*)d_in[9];
    const float* W0 = (const float*)d_in[10];
    const float* b0 = (const float*)d_in[11];
    const float* W1 = (const float*)d_in[12];
    const float* b1 = (const float*)d_in[13];
    const float* W2 = (const float*)d_in[14];
    const float* b2 = (const float*)d_in[15];
    const float* ow1 = (const float*)d_in[16];
    const float* ob1 = (const float*)d_in[17];
    const float* ow2 = (const float*)d_in[18];
    const float* ob2 = (const float*)d_in[19];
    float* out = (float*)d_out;

    // workspace layout (~83 MB) -- fp16 h buffers, no aliasing needed
    char* w = (char*)d_ws;
    _Float16* hA  = (_Float16*)w;  w += (size_t)(NN + 1) * 64 * 2;   // 12.8 MB (+zero row)
    _Float16* hB  = (_Float16*)w;  w += (size_t)(NN + 1) * 64 * 2;   // 12.8 MB (+zero row)
    int*   col    = (int*)w;    w += (size_t)NE * 4;                 // 12.8 MB
    v2i*   pairs  = (v2i*)w;    w += (size_t)NBUCK * SLACK * 8;      // 42 MB
    v2i*   povf   = (v2i*)w;    w += (size_t)NBUCK * OVFCAP * 8;     // 1 MB
    float* dinv   = (float*)w;  w += (size_t)NN * 4;
    int*   rowptr = (int*)w;    w += (size_t)(NN + 1) * 4;
    int*   bctl   = (int*)w;    w += (size_t)NBUCK * 16 * 4;         // 16 KB (padded lines)
    int*   bbase  = (int*)w;    w += (size_t)NBUCK * 4;

    // ---- CSR build (two-phase, line-staged; reused by all 3 layers) ----
    hipMemsetAsync(bctl, 0, (size_t)NBUCK * 16 * 4, stream);
    // sentinel zero rows
    hipMemsetAsync(hA + (size_t)NN * 64, 0, 64 * 2, stream);
    hipMemsetAsync(hB + (size_t)NN * 64, 0, 64 * 2, stream);
    partition_kernel<<<P1_GRID, 256, 0, stream>>>(src, dst, bctl, pairs, povf);
    bucket_scan_kernel<<<1, NBUCK, 0, stream>>>(bctl, bbase, rowptr);
    csr_fill_kernel<<<NBUCK, 256, 0, stream>>>(pairs, povf, bctl, bbase, rowptr, dinv, col);

    // ---- layer 0: fused encoders + matmul (scaled) -> hA ----
    encmm0_kernel<<<(NN + 63) / 64, 256, 0, stream>>>(xf, xw, xt, Wf, bf, Ww, bw, Wt, bt, W0, dinv, hA);
    // ---- gather(b0) + mm(W1) : hA -> hB ----
    gather_mm_kernel<<<(NN * 64 + 255) / 256, 256, 0, stream>>>(col, rowptr, dinv, hA, b0, W1, hB);
    // ---- gather(b1) + mm(W2) : hB -> hA ----
    gather_mm_kernel<<<(NN * 64 + 255) / 256, 256, 0, stream>>>(col, rowptr, dinv, hB, b1, W2, hA);
    // ---- gather(b2) + output MLP : hA -> out ----
    gather_mlp_kernel<<<(NN * 64 + 255) / 256, 256, 0, stream>>>(col, rowptr, dinv, hA, b2, ow1, ob1, ow2, ob2, out);
}

// Round 14
// 566.730 us; speedup vs baseline: 2.1002x; 1.0176x over previous
//
#include <hip/hip_runtime.h>

#define NN 100000
#define NE 3200000
#define HD 64

// two-phase CSR build
#define NBUCK 256
#define BWID 392                                    // 256*392 = 100352 >= NN
#define SLACK 20480                                 // slots/bucket: 12544 real + ~5500 pad + margin
#define COLCAP 13568                                // real cols/bucket cap (12544 + ~9 sigma)
#define OVFCAP 512                                  // overflow pairs/bucket
#define CAP 16                                      // staged pairs per bucket per block
#define P1_EPB 2048                                 // edges per partition block
#define P1_GRID ((NE + P1_EPB - 1) / P1_EPB)        // 1563

typedef int      v4i __attribute__((ext_vector_type(4)));
typedef int      v2i __attribute__((ext_vector_type(2)));
typedef _Float16 h4f __attribute__((ext_vector_type(4)));   // 4 halves = 8 B

__device__ __forceinline__ void fma4(float4& a, float s, const float4& b) {
    a.x = fmaf(s, b.x, a.x); a.y = fmaf(s, b.y, a.y);
    a.z = fmaf(s, b.z, a.z); a.w = fmaf(s, b.w, a.w);
}
__device__ __forceinline__ void addh4(float4& a, const h4f& b) {
    a.x += (float)b[0]; a.y += (float)b[1]; a.z += (float)b[2]; a.w += (float)b[3];
}

// ---------------- phase 1: bucket partition, LDS-staged, 1 drain/block ----------------
__global__ void __launch_bounds__(256) partition_kernel(
    const int* __restrict__ src, const int* __restrict__ dst,
    int* __restrict__ bctl, v2i* __restrict__ pairs, v2i* __restrict__ povf) {
    __shared__ v2i stage[NBUCK][CAP];
    __shared__ int cnt[NBUCK];
    int t = threadIdx.x;
    cnt[t] = 0;                         // NBUCK == blockDim == 256
    __syncthreads();
    const v4i* d4p = (const v4i*)dst;
    const v4i* s4p = (const v4i*)src;
    const int NE4 = NE / 4;
    int base4 = blockIdx.x * (P1_EPB / 4);
    #pragma unroll
    for (int it = 0; it < P1_EPB / 1024; it++) {
        int i = base4 + it * 256 + t;
        v4i d4 = (v4i){-1, -1, -1, -1};
        v4i s4 = (v4i){0, 0, 0, 0};
        if (i < NE4) {
            d4 = __builtin_nontemporal_load(d4p + i);
            s4 = __builtin_nontemporal_load(s4p + i);
        }
        #pragma unroll
        for (int k = 0; k < 4; k++) {
            int d = d4[k];
            if (d >= 0) {
                int b = (unsigned)d / BWID;
                int slot = atomicAdd(&cnt[b], 1);
                v2i p; p[0] = s4[k]; p[1] = d;
                if (slot < CAP) {
                    stage[b][slot] = p;
                } else {                 // rare overflow -> separate region
                    int o = atomicAdd(&bctl[b * 16 + 2], 1);
                    if (o < OVFCAP) povf[(size_t)b * OVFCAP + o] = p;
                }
            }
        }
    }
    __syncthreads();
    // drain bucket t (single drain per block)
    int c_tot = cnt[t];
    int c = (c_tot > CAP) ? CAP : c_tot;
    int runs = (c + 7) >> 3;             // 0..2
    if (runs) {
        int slots = runs * 8;            // 8 or 16, <= CAP
        for (int m = c; m < slots; m++) { v2i p; p[0] = 0; p[1] = -1; stage[t][m] = p; }
        int gb = atomicAdd(&bctl[t * 16], slots);   // stays multiple of 8
        if (gb + slots <= SLACK) {
            v4i* gp = (v4i*)(pairs + (size_t)t * SLACK + gb);
            const v4i* sp = (const v4i*)&stage[t][0];
            #pragma unroll
            for (int m = 0; m < 8; m++) { if (m < runs * 4) gp[m] = sp[m]; }
        } else {
            for (int m = 0; m < slots && gb + m < SLACK; m++)
                pairs[(size_t)t * SLACK + gb + m] = stage[t][m];
        }
    }
    if (c_tot > 0) atomicAdd(&bctl[t * 16 + 1], c_tot);   // real contribution
}

// ---------------- tiny scan over real bucket counts ----------------
__global__ void bucket_scan_kernel(const int* __restrict__ bctl,
                                   int* __restrict__ bbase, int* __restrict__ rowptr) {
    __shared__ int s[NBUCK];
    int t = threadIdx.x;
    int v = bctl[t * 16 + 1];
    s[t] = v; __syncthreads();
    for (int off = 1; off < NBUCK; off <<= 1) {
        int x = (t >= off) ? s[t - off] : 0;
        __syncthreads();
        s[t] += x;
        __syncthreads();
    }
    bbase[t] = s[t] - v;                 // exclusive prefix of real counts
    if (t == NBUCK - 1) rowptr[NN] = s[t];   // == NE
}

// ---------------- phase 2: per-bucket hist + scan + LDS scatter ----------------
__global__ void __launch_bounds__(256) csr_fill_kernel(
    const v2i* __restrict__ pairs, const v2i* __restrict__ povf,
    const int* __restrict__ bctl, const int* __restrict__ bbase,
    int* __restrict__ rowptr, float* __restrict__ dinv, int* __restrict__ col) {
    __shared__ int hist[BWID];
    __shared__ int rp[BWID];
    __shared__ int cur[BWID];
    __shared__ int sc[256];
    __shared__ int cols[COLCAP];
    int b = blockIdx.x, t = threadIdx.x;
    int lo = b * BWID;
    int hi = min(lo + BWID, NN);
    int nw = hi - lo;
    for (int i = t; i < BWID; i += 256) { hist[i] = 0; cur[i] = 0; }
    __syncthreads();
    int np = bctl[b * 16];     if (np > SLACK) np = SLACK;
    int nov = bctl[b * 16 + 2]; if (nov > OVFCAP) nov = OVFCAP;
    int base = bbase[b];
    const v2i* pb = pairs + (size_t)b * SLACK;
    const v2i* ob = povf + (size_t)b * OVFCAP;
    // pass 1: histogram (skip sentinels)
    for (int i = t; i < np; i += 256) {
        v2i p = pb[i];
        if (p[1] >= 0) atomicAdd(&hist[p[1] - lo], 1);
    }
    for (int i = t; i < nov; i += 256) {
        v2i p = ob[i];
        atomicAdd(&hist[p[1] - lo], 1);
    }
    __syncthreads();
    // exclusive scan of hist -> rp (2 elements per thread)
    int h0 = 0, s2 = 0;
    if (2 * t < BWID) {
        h0 = hist[2 * t];
        int h1 = (2 * t + 1 < BWID) ? hist[2 * t + 1] : 0;
        s2 = h0 + h1;
    }
    sc[t] = s2; __syncthreads();
    for (int off = 1; off < 256; off <<= 1) {
        int x = (t >= off) ? sc[t - off] : 0;
        __syncthreads();
        sc[t] += x;
        __syncthreads();
    }
    if (2 * t < BWID) {
        int ex = sc[t] - s2;
        rp[2 * t] = ex;
        if (2 * t + 1 < BWID) rp[2 * t + 1] = ex + h0;
    }
    __syncthreads();
    // rowptr + dinv slices (coalesced)
    for (int i = t; i < nw; i += 256) {
        rowptr[lo + i] = base + rp[i];
        dinv[lo + i] = 1.0f / sqrtf((float)(hist[i] + 1));  // +1 self-loop
    }
    // pass 2: scatter into LDS
    for (int i = t; i < np; i += 256) {
        v2i p = pb[i];
        if (p[1] >= 0) {
            int li = p[1] - lo;
            int slot = atomicAdd(&cur[li], 1);
            int o = rp[li] + slot;
            if (o < COLCAP) cols[o] = p[0];
        }
    }
    for (int i = t; i < nov; i += 256) {
        v2i p = ob[i];
        int li = p[1] - lo;
        int slot = atomicAdd(&cur[li], 1);
        int o = rp[li] + slot;
        if (o < COLCAP) cols[o] = p[0];
    }
    __syncthreads();
    // contiguous col write (real count only)
    int nreal = bctl[b * 16 + 1]; if (nreal > COLCAP) nreal = COLCAP;
    for (int i = t; i < nreal; i += 256)
        col[base + i] = cols[i];
}

// ---------------- fused modality encoders + GCN layer-0 matmul ----------------
// Computes in fp32, stores hs = h*dinv as FP16.
__global__ void __launch_bounds__(256) encmm0_kernel(
    const float* __restrict__ xf, const float* __restrict__ xw, const float* __restrict__ xt,
    const float* __restrict__ Wf, const float* __restrict__ bf,
    const float* __restrict__ Ww, const float* __restrict__ bw,
    const float* __restrict__ Wt, const float* __restrict__ bt,
    const float* __restrict__ W0, const float* __restrict__ dinv,
    _Float16* __restrict__ h) {
    __shared__ float xin[64][32];    // fire[0..7], wea[8..19], ter[20..29]
    __shared__ float wenc[30][64];   // encoder weights (rows match xin cols)
    __shared__ float bs[192];        // encoder biases
    __shared__ float xs[64][36];     // encoder outputs for current 32-slice (+4 pad)
    __shared__ float ws[32][64];     // W0 rows for current slice
    int t = threadIdx.x;
    int n0 = blockIdx.x * 64;

    {   // stage raw inputs
        const float4* xf4 = (const float4*)xf;
        for (int i = t; i < 128; i += 256) {
            int n = i >> 1, q = i & 1;
            int gn = n0 + n;
            float4 v = make_float4(0, 0, 0, 0);
            if (gn < NN) v = xf4[(size_t)gn * 2 + q];
            *(float4*)&xin[n][q * 4] = v;
        }
        const float4* xw4 = (const float4*)xw;
        for (int i = t; i < 192; i += 256) {
            int n = i / 3, q = i - n * 3;
            int gn = n0 + n;
            float4 v = make_float4(0, 0, 0, 0);
            if (gn < NN) v = xw4[(size_t)gn * 3 + q];
            *(float4*)&xin[n][8 + q * 4] = v;
        }
        const float2* xt2 = (const float2*)xt;
        for (int i = t; i < 320; i += 256) {
            int n = i / 5, q = i - n * 5;
            int gn = n0 + n;
            float2 v = make_float2(0, 0);
            if (gn < NN) v = xt2[(size_t)gn * 5 + q];
            *(float2*)&xin[n][20 + q * 2] = v;
        }
        // stage encoder weights: rows 0-7 Wf, 8-19 Ww, 20-29 Wt
        for (int i = t; i < 480; i += 256) {
            int r = i >> 4, q = i & 15;
            float4 v;
            if (r < 8)       v = ((const float4*)Wf)[r * 16 + q];
            else if (r < 20) v = ((const float4*)Ww)[(r - 8) * 16 + q];
            else             v = ((const float4*)Wt)[(r - 20) * 16 + q];
            *(float4*)&wenc[r][q * 4] = v;
        }
        // stage encoder biases
        if (t < 192) bs[t] = (t < 64) ? bf[t] : (t < 128) ? bw[t - 64] : bt[t - 128];
    }

    int cg = t & 15, ng = t >> 4;
    int c0 = cg * 4;
    float4 acc[4];
    #pragma unroll
    for (int i = 0; i < 4; i++) acc[i] = make_float4(0, 0, 0, 0);

    for (int kq = 0; kq < 6; kq++) {
        __syncthreads();
        {   // stage W0 slice rows [kq*32, kq*32+32)
            const float4* W04 = (const float4*)W0;
            float4* ws4 = (float4*)&ws[0][0];
            for (int i = t; i < 512; i += 256)
                ws4[i] = W04[(size_t)kq * 512 + i];
        }
        // compute encoder outputs for this slice (uniform modality per kq)
        int coff = (kq < 2) ? kq * 32 : (kq < 4) ? (kq - 2) * 32 : (kq - 4) * 32;
        if (kq < 2) {
            for (int i = t; i < 2048; i += 256) {
                int n = i >> 5, kk = i & 31;
                float a = bs[kq * 32 + kk];
                #pragma unroll
                for (int k = 0; k < 8; k++) a = fmaf(xin[n][k], wenc[k][coff + kk], a);
                xs[n][kk] = fmaxf(a, 0.f);
            }
        } else if (kq < 4) {
            for (int i = t; i < 2048; i += 256) {
                int n = i >> 5, kk = i & 31;
                float a = bs[kq * 32 + kk];
                #pragma unroll
                for (int k = 0; k < 12; k++) a = fmaf(xin[n][8 + k], wenc[8 + k][coff + kk], a);
                xs[n][kk] = fmaxf(a, 0.f);
            }
        } else {
            for (int i = t; i < 2048; i += 256) {
                int n = i >> 5, kk = i & 31;
                float a = bs[kq * 32 + kk];
                #pragma unroll
                for (int k = 0; k < 10; k++) a = fmaf(xin[n][20 + k], wenc[20 + k][coff + kk], a);
                xs[n][kk] = fmaxf(a, 0.f);
            }
        }
        __syncthreads();
        // register-blocked fma over this 32-slice
        for (int k = 0; k < 32; k += 4) {
            float4 b0 = *(const float4*)&ws[k + 0][c0];
            float4 b1 = *(const float4*)&ws[k + 1][c0];
            float4 b2 = *(const float4*)&ws[k + 2][c0];
            float4 b3 = *(const float4*)&ws[k + 3][c0];
            #pragma unroll
            for (int i = 0; i < 4; i++) {
                float4 a = *(const float4*)&xs[ng * 4 + i][k];
                fma4(acc[i], a.x, b0); fma4(acc[i], a.y, b1);
                fma4(acc[i], a.z, b2); fma4(acc[i], a.w, b3);
            }
        }
    }
    h4f* h4 = (h4f*)h;
    #pragma unroll
    for (int i = 0; i < 4; i++) {
        int gn = n0 + ng * 4 + i;
        if (gn < NN) {
            float dn = dinv[gn];
            h4f v;
            v[0] = (_Float16)(acc[i].x * dn);
            v[1] = (_Float16)(acc[i].y * dn);
            v[2] = (_Float16)(acc[i].z * dn);
            v[3] = (_Float16)(acc[i].w * dn);
            h4[((unsigned)gn << 4) + cg] = v;
        }
    }
}

#define GATHER_BODY(E)                                              \
    {   int s_ = __shfl(pv, (E));                                   \
        h4f v_ = h4[((unsigned)s_ << 4) + q];                       \
        addh4(acc, v_); }

// ---------------- fused CSR gather + finalize + next-layer 64x64 matmul ----------------
// One node per wave; fp16 h rows; 32-bit gathered addressing (h is 12.8 MB ->
// SADDR+voffset loads, no per-lane 64-bit math); 8-deep unroll tier so the
// typical deg-32 node issues all 8 row-loads in ONE latency round; self-row /
// bias / dinv hoisted ahead of the gather as extra in-flight loads.
__global__ void gather_mm_kernel(
    const int* __restrict__ col, const int* __restrict__ rowptr,
    const float* __restrict__ dinv, const _Float16* __restrict__ h,
    const float* __restrict__ bias, const float* __restrict__ W,
    _Float16* __restrict__ hout) {
    int t = threadIdx.x;
    int n = (blockIdx.x * 256 + t) >> 6;
    int l = t & 63;
    if (n >= NN) return;
    int g = l >> 4;      // edge sub-slot 0..3
    int q = l & 15;      // half4 slot 0..15
    const h4f* h4 = (const h4f*)h;
    // hoisted independent loads (in flight under the gather)
    float dn = dinv[n];
    h4f hnh = h4[((unsigned)n << 4) + q];
    float4 b4 = ((const float4*)bias)[q];
    float4 acc = make_float4(0, 0, 0, 0);
    int r0 = rowptr[n], r1 = rowptr[n + 1];
    for (int base = r0; base < r1; base += 64) {
        int cnt = min(64, r1 - base);
        int pv = NN;                          // sentinel: zero row
        if (l < cnt) pv = __builtin_nontemporal_load(col + base + l);
        int steps = (cnt + 3) >> 2;
        int j = 0;
        for (; j + 8 <= steps; j += 8) {      // 8 loads in flight (deg>=32 fast path)
            int s0 = __shfl(pv, (j + 0) * 4 + g);
            int s1 = __shfl(pv, (j + 1) * 4 + g);
            int s2 = __shfl(pv, (j + 2) * 4 + g);
            int s3 = __shfl(pv, (j + 3) * 4 + g);
            int s4 = __shfl(pv, (j + 4) * 4 + g);
            int s5 = __shfl(pv, (j + 5) * 4 + g);
            int s6 = __shfl(pv, (j + 6) * 4 + g);
            int s7 = __shfl(pv, (j + 7) * 4 + g);
            h4f v0 = h4[((unsigned)s0 << 4) + q];
            h4f v1 = h4[((unsigned)s1 << 4) + q];
            h4f v2 = h4[((unsigned)s2 << 4) + q];
            h4f v3 = h4[((unsigned)s3 << 4) + q];
            h4f v4 = h4[((unsigned)s4 << 4) + q];
            h4f v5 = h4[((unsigned)s5 << 4) + q];
            h4f v6 = h4[((unsigned)s6 << 4) + q];
            h4f v7 = h4[((unsigned)s7 << 4) + q];
            addh4(acc, v0); addh4(acc, v1); addh4(acc, v2); addh4(acc, v3);
            addh4(acc, v4); addh4(acc, v5); addh4(acc, v6); addh4(acc, v7);
        }
        for (; j + 4 <= steps; j += 4) {      // at most one
            int s0 = __shfl(pv, (j + 0) * 4 + g);
            int s1 = __shfl(pv, (j + 1) * 4 + g);
            int s2 = __shfl(pv, (j + 2) * 4 + g);
            int s3 = __shfl(pv, (j + 3) * 4 + g);
            h4f v0 = h4[((unsigned)s0 << 4) + q];
            h4f v1 = h4[((unsigned)s1 << 4) + q];
            h4f v2 = h4[((unsigned)s2 << 4) + q];
            h4f v3 = h4[((unsigned)s3 << 4) + q];
            addh4(acc, v0); addh4(acc, v1); addh4(acc, v2); addh4(acc, v3);
        }
        for (; j < steps; j++)                // at most 3
            GATHER_BODY(j * 4 + g)
    }
    acc.x += __shfl_xor(acc.x, 16); acc.y += __shfl_xor(acc.y, 16);
    acc.z += __shfl_xor(acc.z, 16); acc.w += __shfl_xor(acc.w, 16);
    acc.x += __shfl_xor(acc.x, 32); acc.y += __shfl_xor(acc.y, 32);
    acc.z += __shfl_xor(acc.z, 32); acc.w += __shfl_xor(acc.w, 32);
    // layer output r (all lanes; q-slot replicated)
    float4 r;
    r.x = fmaxf(fmaf(dn, acc.x + (float)hnh[0], b4.x), 0.f);
    r.y = fmaxf(fmaf(dn, acc.y + (float)hnh[1], b4.y), 0.f);
    r.z = fmaxf(fmaf(dn, acc.z + (float)hnh[2], b4.z), 0.f);
    r.w = fmaxf(fmaf(dn, acc.w + (float)hnh[3], b4.w), 0.f);
    // next-layer matmul: lane l computes output column l; W rows from L1
    float oc0 = 0.f, oc1 = 0.f, oc2 = 0.f, oc3 = 0.f;
    #pragma unroll
    for (int qq = 0; qq < 16; qq++) {
        float rx = __shfl(r.x, qq);
        float ry = __shfl(r.y, qq);
        float rz = __shfl(r.z, qq);
        float rw = __shfl(r.w, qq);
        oc0 = fmaf(rx, W[(qq * 4 + 0) * 64 + l], oc0);
        oc1 = fmaf(ry, W[(qq * 4 + 1) * 64 + l], oc1);
        oc2 = fmaf(rz, W[(qq * 4 + 2) * 64 + l], oc2);
        oc3 = fmaf(rw, W[(qq * 4 + 3) * 64 + l], oc3);
    }
    float oc = (oc0 + oc1) + (oc2 + oc3);
    __builtin_nontemporal_store((_Float16)(oc * dn), &hout[((unsigned)n << 6) + l]);
}

// ---------------- fused CSR gather + finalize + output MLP ----------------
__global__ void gather_mlp_kernel(
    const int* __restrict__ col, const int* __restrict__ rowptr,
    const float* __restrict__ dinv, const _Float16* __restrict__ h,
    const float* __restrict__ bias, const float* __restrict__ w1,
    const float* __restrict__ b1, const float* __restrict__ w2,
    const float* __restrict__ b2, float* __restrict__ out) {
    int t = threadIdx.x;
    int n = (blockIdx.x * 256 + t) >> 6;
    int l = t & 63;
    if (n >= NN) return;
    int g = l >> 4;
    int q = l & 15;
    const h4f* h4 = (const h4f*)h;
    float dn = dinv[n];
    h4f hnh = h4[((unsigned)n << 4) + q];
    float4 b4 = ((const float4*)bias)[q];
    float4 acc = make_float4(0, 0, 0, 0);
    int r0 = rowptr[n], r1 = rowptr[n + 1];
    for (int base = r0; base < r1; base += 64) {
        int cnt = min(64, r1 - base);
        int pv = NN;
        if (l < cnt) pv = __builtin_nontemporal_load(col + base + l);
        int steps = (cnt + 3) >> 2;
        int j = 0;
        for (; j + 8 <= steps; j += 8) {
            int s0 = __shfl(pv, (j + 0) * 4 + g);
            int s1 = __shfl(pv, (j + 1) * 4 + g);
            int s2 = __shfl(pv, (j + 2) * 4 + g);
            int s3 = __shfl(pv, (j + 3) * 4 + g);
            int s4 = __shfl(pv, (j + 4) * 4 + g);
            int s5 = __shfl(pv, (j + 5) * 4 + g);
            int s6 = __shfl(pv, (j + 6) * 4 + g);
            int s7 = __shfl(pv, (j + 7) * 4 + g);
            h4f v0 = h4[((unsigned)s0 << 4) + q];
            h4f v1 = h4[((unsigned)s1 << 4) + q];
            h4f v2 = h4[((unsigned)s2 << 4) + q];
            h4f v3 = h4[((unsigned)s3 << 4) + q];
            h4f v4 = h4[((unsigned)s4 << 4) + q];
            h4f v5 = h4[((unsigned)s5 << 4) + q];
            h4f v6 = h4[((unsigned)s6 << 4) + q];
            h4f v7 = h4[((unsigned)s7 << 4) + q];
            addh4(acc, v0); addh4(acc, v1); addh4(acc, v2); addh4(acc, v3);
            addh4(acc, v4); addh4(acc, v5); addh4(acc, v6); addh4(acc, v7);
        }
        for (; j + 4 <= steps; j += 4) {
            int s0 = __shfl(pv, (j + 0) * 4 + g);
            int s1 = __shfl(pv, (j + 1) * 4 + g);
            int s2 = __shfl(pv, (j + 2) * 4 + g);
            int s3 = __shfl(pv, (j + 3) * 4 + g);
            h4f v0 = h4[((unsigned)s0 << 4) + q];
            h4f v1 = h4[((unsigned)s1 << 4) + q];
            h4f v2 = h4[((unsigned)s2 << 4) + q];
            h4f v3 = h4[((unsigned)s3 << 4) + q];
            addh4(acc, v0); addh4(acc, v1); addh4(acc, v2); addh4(acc, v3);
        }
        for (; j < steps; j++)
            GATHER_BODY(j * 4 + g)
    }
    acc.x += __shfl_xor(acc.x, 16); acc.y += __shfl_xor(acc.y, 16);
    acc.z += __shfl_xor(acc.z, 16); acc.w += __shfl_xor(acc.w, 16);
    acc.x += __shfl_xor(acc.x, 32); acc.y += __shfl_xor(acc.y, 32);
    acc.z += __shfl_xor(acc.z, 32); acc.w += __shfl_xor(acc.w, 32);
    float4 r;
    r.x = fmaxf(fmaf(dn, acc.x + (float)hnh[0], b4.x), 0.f);
    r.y = fmaxf(fmaf(dn, acc.y + (float)hnh[1], b4.y), 0.f);
    r.z = fmaxf(fmaf(dn, acc.z + (float)hnh[2], b4.z), 0.f);
    r.w = fmaxf(fmaf(dn, acc.w + (float)hnh[3], b4.w), 0.f);
    // output MLP: hidden unit c = l&31 (w1 rows are L1-resident, coalesced)
    int c = l & 31;
    float a0 = b1[c], a1 = 0.f, a2p = 0.f, a3 = 0.f;
    #pragma unroll
    for (int qq = 0; qq < 16; qq++) {
        float rx = __shfl(r.x, qq);
        float ry = __shfl(r.y, qq);
        float rz = __shfl(r.z, qq);
        float rw = __shfl(r.w, qq);
        a0  = fmaf(rx, w1[(qq * 4 + 0) * 32 + c], a0);
        a1  = fmaf(ry, w1[(qq * 4 + 1) * 32 + c], a1);
        a2p = fmaf(rz, w1[(qq * 4 + 2) * 32 + c], a2p);
        a3  = fmaf(rw, w1[(qq * 4 + 3) * 32 + c], a3);
    }
    float a = (a0 + a1) + (a2p + a3);
    float v = fmaxf(a, 0.f) * w2[c];
    v += __shfl_xor(v, 1); v += __shfl_xor(v, 2);
    v += __shfl_xor(v, 4); v += __shfl_xor(v, 8);
    v += __shfl_xor(v, 16);
    if (l == 0) __builtin_nontemporal_store(v + b2[0], &out[n]);
}

extern "C" void kernel_launch(void* const* d_in, const int* in_sizes, int n_in,
                              void* d_out, int out_size, void* d_ws, size_t ws_size,
                              hipStream_t stream) {
    const float* xf = (const float*)d_in[0];
    const float* xw = (const float*)d_in[1];
    const float* xt = (const float*)d_in[2];
    const int*   ei = (const int*)d_in[3];
    const int*   src = ei;
    const int*   dst = ei + NE;
    const float* Wf = (const float*)d_in[4];
    const float* bf = (const float*)d_in[5];
    const float* Ww = (const float*)d_in[6];
    const float* bw = (const float*)d_in[7];
    const float* Wt = (const float*)d_in[8];
    const float* bt = (const float*)d_in[9];
    const float* W0 = (const float*)d_in[10];
    const float* b0 = (const float*)d_in[11];
    const float* W1 = (const float*)d_in[12];
    const float* b1 = (const float*)d_in[13];
    const float* W2 = (const float*)d_in[14];
    const float* b2 = (const float*)d_in[15];
    const float* ow1 = (const float*)d_in[16];
    const float* ob1 = (const float*)d_in[17];
    const float* ow2 = (const float*)d_in[18];
    const float* ob2 = (const float*)d_in[19];
    float* out = (float*)d_out;

    // workspace layout (~83 MB) -- fp16 h buffers
    char* w = (char*)d_ws;
    _Float16* hA  = (_Float16*)w;  w += (size_t)(NN + 1) * 64 * 2;   // 12.8 MB (+zero row)
    _Float16* hB  = (_Float16*)w;  w += (size_t)(NN + 1) * 64 * 2;   // 12.8 MB (+zero row)
    int*   col    = (int*)w;    w += (size_t)NE * 4;                 // 12.8 MB
    v2i*   pairs  = (v2i*)w;    w += (size_t)NBUCK * SLACK * 8;      // 42 MB
    v2i*   povf   = (v2i*)w;    w += (size_t)NBUCK * OVFCAP * 8;     // 1 MB
    float* dinv   = (float*)w;  w += (size_t)NN * 4;
    int*   rowptr = (int*)w;    w += (size_t)(NN + 1) * 4;
    int*   bctl   = (int*)w;    w += (size_t)NBUCK * 16 * 4;         // 16 KB (padded lines)
    int*   bbase  = (int*)w;    w += (size_t)NBUCK * 4;

    // ---- CSR build (two-phase, line-staged; reused by all 3 layers) ----
    hipMemsetAsync(bctl, 0, (size_t)NBUCK * 16 * 4, stream);
    // sentinel zero rows
    hipMemsetAsync(hA + (size_t)NN * 64, 0, 64 * 2, stream);
    hipMemsetAsync(hB + (size_t)NN * 64, 0, 64 * 2, stream);
    partition_kernel<<<P1_GRID, 256, 0, stream>>>(src, dst, bctl, pairs, povf);
    bucket_scan_kernel<<<1, NBUCK, 0, stream>>>(bctl, bbase, rowptr);
    csr_fill_kernel<<<NBUCK, 256, 0, stream>>>(pairs, povf, bctl, bbase, rowptr, dinv, col);

    // ---- layer 0: fused encoders + matmul (scaled) -> hA ----
    encmm0_kernel<<<(NN + 63) / 64, 256, 0, stream>>>(xf, xw, xt, Wf, bf, Ww, bw, Wt, bt, W0, dinv, hA);
    // ---- gather(b0) + mm(W1) : hA -> hB ----
    gather_mm_kernel<<<(NN * 64 + 255) / 256, 256, 0, stream>>>(col, rowptr, dinv, hA, b0, W1, hB);
    // ---- gather(b1) + mm(W2) : hB -> hA ----
    gather_mm_kernel<<<(NN * 64 + 255) / 256, 256, 0, stream>>>(col, rowptr, dinv, hB, b1, W2, hA);
    // ---- gather(b2) + output MLP : hA -> out ----
    gather_mlp_kernel<<<(NN * 64 + 255) / 256, 256, 0, stream>>>(col, rowptr, dinv, hA, b2, ow1, ob1, ow2, ob2, out);
}